// Round 15
// baseline (589.029 us; speedup 1.0000x reference)
//
#include <hip/hip_runtime.h>
#include <hip/hip_fp16.h>

#define EPS 1e-5f

// Problem constants: B=4, C=64, H=128, W=128, N=512, OP2=128, HEAD=8, HP=16
// qk_dim=4, v_dim=8

// workspace layout (float offsets)
//  y1h: (b,l,o,w) half, 8,388,608 halves at 0    [dead after k_tr]
//  av : (n,h,c,p) half, 4,194,304 halves at 0    (k5 writes; y1h region)
//  avp: (n,h,c,p) half at float-offset 2,097,152
//  Pb3: k3 partials 4096*6 f32 at 4,200,000
//  Vbuf: k5 partials 4096*4 f32 at 4,250,000
//  Pbuf: k1 partials 512*256 f32 at 4,300,000
//  y2h: (n,h,slot,l) packed half2 per uint, 1,048,576 uints at 8,388,608
//  S  : stats 1024 f32 at 16,777,216
//  pos_h: packed qk-pos [u][4 uints] at 16,778,240
//  PT : f32 window tables at 16,781,312
//  vpxg: flat vpx table (sel-shifted), 3084 uints at 16,785,000

typedef _Float16 half2_t __attribute__((ext_vector_type(2)));

__device__ __constant__ int pair_c [10] = {0,0,0,0,1,1,1,2,2,3};
__device__ __constant__ int pair_cp[10] = {0,1,2,3,1,2,3,2,3,3};

__device__ inline float fdot2(half2_t a, half2_t b, float c) {
#if __has_builtin(__builtin_amdgcn_fdot2)
  return __builtin_amdgcn_fdot2(a, b, c, false);
#else
  return c + (float)a[0] * (float)b[0] + (float)a[1] * (float)b[1];
#endif
}
__device__ inline half2_t bch2(unsigned u) {
  union { unsigned u; half2_t h; } x; x.u = u; return x.h;
}
__device__ inline unsigned bcu(half2_t h) {
  union { unsigned u; half2_t h; } x; x.h = h; return x.u;
}
__device__ inline unsigned packf2(float a, float b) {
  half2_t h; h[0] = (_Float16)a; h[1] = (_Float16)b;
  union { unsigned u; half2_t h; } x; x.h = h; return x.u;
}
__device__ inline unsigned pkmul(unsigned u, half2_t c) {
  return bcu(bch2(u) * c);
}

// ---------------- K1: qkv GEMM (half2 dot2) + relu + bn1 partials -----------
__global__ __launch_bounds__(256) void k1_gemm(
    const float* __restrict__ x, const float* __restrict__ wq,
    _Float16* __restrict__ y1h, float* __restrict__ Pbuf)
{
  __shared__ unsigned xs[32][132];
  const int b = blockIdx.x >> 7, l = blockIdx.x & 127;
  const int tid = threadIdx.x;
  const float* xp = x + (size_t)b * 1048576 + (size_t)l * 128;
  for (int idx = tid; idx < 1024; idx += 256) {
    int cp = idx >> 5, w4 = (idx & 31) * 4;
    float4 r0 = *(const float4*)&xp[(2 * cp) * 16384 + w4];
    float4 r1 = *(const float4*)&xp[(2 * cp + 1) * 16384 + w4];
    uint4 o;
    o.x = packf2(r0.x, r1.x); o.y = packf2(r0.y, r1.y);
    o.z = packf2(r0.z, r1.z); o.w = packf2(r0.w, r1.w);
    *(uint4*)&xs[cp][w4] = o;
  }
  __syncthreads();
  const int ty = tid >> 4, tx = tid & 15;
  const int o0 = ty * 8, w0 = tx * 4;
  float acc[8][8];
#pragma unroll
  for (int u = 0; u < 8; ++u)
#pragma unroll
    for (int v = 0; v < 8; ++v) acc[u][v] = 0.f;

  for (int c4 = 0; c4 < 64; c4 += 4) {
    unsigned wr[8][2];
#pragma unroll
    for (int u = 0; u < 8; ++u) {
      float4 wv = *(const float4*)&wq[(o0 + u) * 64 + c4];
      wr[u][0] = packf2(wv.x, wv.y);
      wr[u][1] = packf2(wv.z, wv.w);
    }
    const int cp0 = c4 >> 1;
#pragma unroll
    for (int d = 0; d < 2; ++d) {
      uint4 xa = *(const uint4*)&xs[cp0 + d][w0];
      uint4 xb = *(const uint4*)&xs[cp0 + d][w0 + 64];
      half2_t a0 = bch2(xa.x), a1 = bch2(xa.y), a2 = bch2(xa.z), a3 = bch2(xa.w);
      half2_t b0 = bch2(xb.x), b1 = bch2(xb.y), b2 = bch2(xb.z), b3 = bch2(xb.w);
#pragma unroll
      for (int u = 0; u < 8; ++u) {
        half2_t wh = bch2(wr[u][d]);
        acc[u][0] = fdot2(wh, a0, acc[u][0]);
        acc[u][1] = fdot2(wh, a1, acc[u][1]);
        acc[u][2] = fdot2(wh, a2, acc[u][2]);
        acc[u][3] = fdot2(wh, a3, acc[u][3]);
        acc[u][4] = fdot2(wh, b0, acc[u][4]);
        acc[u][5] = fdot2(wh, b1, acc[u][5]);
        acc[u][6] = fdot2(wh, b2, acc[u][6]);
        acc[u][7] = fdot2(wh, b3, acc[u][7]);
      }
    }
  }
  _Float16* y1p = y1h + (size_t)(b * 128 + l) * 16384;
#pragma unroll
  for (int u = 0; u < 8; ++u) {
#pragma unroll
    for (int v = 0; v < 8; ++v) acc[u][v] = fmaxf(acc[u][v], 0.f);
    uint2 pa, pb;
    pa.x = packf2(acc[u][0], acc[u][1]); pa.y = packf2(acc[u][2], acc[u][3]);
    pb.x = packf2(acc[u][4], acc[u][5]); pb.y = packf2(acc[u][6], acc[u][7]);
    *(uint2*)&y1p[(o0 + u) * 128 + w0] = pa;
    *(uint2*)&y1p[(o0 + u) * 128 + w0 + 64] = pb;
    float s  = acc[u][0] + acc[u][1] + acc[u][2] + acc[u][3]
             + acc[u][4] + acc[u][5] + acc[u][6] + acc[u][7];
    float ss = acc[u][0]*acc[u][0] + acc[u][1]*acc[u][1] + acc[u][2]*acc[u][2]
             + acc[u][3]*acc[u][3] + acc[u][4]*acc[u][4] + acc[u][5]*acc[u][5]
             + acc[u][6]*acc[u][6] + acc[u][7]*acc[u][7];
#pragma unroll
    for (int off = 1; off < 16; off <<= 1) {
      s  += __shfl_xor(s, off);
      ss += __shfl_xor(ss, off);
    }
    if (tx == 0) {
      Pbuf[blockIdx.x * 256 + o0 + u] = s;
      Pbuf[blockIdx.x * 256 + 128 + o0 + u] = ss;
    }
  }
}

// ---------------- K_tr: y1h -> y2h (BN stats reduced in-block, applied) -----
__global__ __launch_bounds__(256) void k_tr(
    const _Float16* __restrict__ y1h, const float* __restrict__ Pbuf,
    const float* __restrict__ g1, const float* __restrict__ b1,
    unsigned* __restrict__ y2h)
{
  __shared__ _Float16 th[2][64][134];
  __shared__ float scsh[4];
  const int s = blockIdx.x & 63, b = blockIdx.x >> 6;
  const int h = s >> 3, slot = s & 7;
  const int o0 = 2 * s, o1 = 2 * s + 1;
  const int tid = threadIdx.x;
  {
    int r = tid >> 6, lane = tid & 63;
    int row = ((r & 1) ? o1 : o0) + (r >> 1) * 128;
    float a = 0.f;
#pragma unroll
    for (int m = 0; m < 8; ++m) a += Pbuf[(lane + 64 * m) * 256 + row];
#pragma unroll
    for (int off = 1; off < 64; off <<= 1) a += __shfl_xor(a, off);
    if (lane == 0) scsh[r] = a;
  }
  __syncthreads();
  const float inv = 1.f / 65536.f;
  const float m0 = scsh[0] * inv, v0 = scsh[2] * inv - m0 * m0;
  const float m1 = scsh[1] * inv, v1 = scsh[3] * inv - m1 * m1;
  const float sc0 = g1[o0] * rsqrtf(v0 + EPS), sh0 = b1[o0] - m0 * sc0;
  const float sc1 = g1[o1] * rsqrtf(v1 + EPS), sh1 = b1[o1] - m1 * sc1;
  for (int lh = 0; lh < 2; ++lh) {
    const int l0 = lh * 64;
    for (int idx = tid; idx < 4096; idx += 256) {
      int ll = idx >> 6, wp = idx & 63;
      size_t base = ((size_t)(b * 128 + l0 + ll) * 128) * 128 + 2 * wp;
      unsigned a0 = *(const unsigned*)&y1h[base + (size_t)o0 * 128];
      unsigned a1 = *(const unsigned*)&y1h[base + (size_t)o1 * 128];
      half2_t ha = bch2(a0), hb = bch2(a1);
      *(unsigned*)&th[0][ll][2 * wp] =
          packf2((float)ha[0] * sc0 + sh0, (float)ha[1] * sc0 + sh0);
      *(unsigned*)&th[1][ll][2 * wp] =
          packf2((float)hb[0] * sc1 + sh1, (float)hb[1] * sc1 + sh1);
    }
    __syncthreads();
    for (int idx = tid; idx < 8192; idx += 256) {
      int w = idx >> 6, ll = idx & 63;
      unsigned pk;
      { half2_t hh; hh[0] = th[0][ll][w]; hh[1] = th[1][ll][w];
        union { unsigned u; half2_t h; } xx; xx.h = hh; pk = xx.u; }
      y2h[((size_t)((b * 128 + w) * 8 + h) * 8 + slot) * 128 + l0 + ll] = pk;
    }
    __syncthreads();
  }
}

// ---------------- K0: PT tables + packed qk-pos + vpx tables ----------------
__global__ __launch_bounds__(128) void k0_pos(const float* __restrict__ pos,
                                              float* __restrict__ PT,
                                              unsigned* __restrict__ pos_h,
                                              unsigned* __restrict__ vpxg)
{
  const int blk = blockIdx.x, tid = threadIdx.x;
  if (blk == 28) {
    for (int u = tid; u < 255; u += 128) {
#pragma unroll
      for (int s = 0; s < 4; ++s)
        pos_h[u * 4 + s] = packf2(pos[(2 * s) * 255 + u], pos[(2 * s + 1) * 255 + u]);
    }
    return;
  }
  if (blk == 29) {
    for (int m = tid; m < 3084; m += 128) {
      int sel = m / 1540, rem = m - sel * 1540;
      unsigned val = 0;
      if (sel < 2 && rem < 1536) {
        int rp = rem / 12, c = rem % 12;
        if (c < 8) {
          int ua = (sel ? 254 : 253) - 2 * rp;
          int ub = ua - 1;
          float fa = (ua >= 0) ? pos[(8 + c) * 255 + ua] : 0.f;
          float fb = (ub >= 0) ? pos[(8 + c) * 255 + ub] : 0.f;
          val = packf2(fa, fb);
        }
      }
      vpxg[m] = val;
    }
    return;
  }
  __shared__ float r0[255], r1[255];
  int rowA, rowB, out;
  bool prod;
  if (blk < 4)       { rowA = blk;                 rowB = rowA;               out = blk * 128;              prod = false; }
  else if (blk < 14) { int m = blk - 4;  rowA = pair_c[m];     rowB = pair_cp[m];     out = 1024 + m * 128; prod = true; }
  else if (blk < 18) { rowA = 4 + (blk - 14);      rowB = rowA;               out = 512 + (blk - 14) * 128; prod = false; }
  else               { int m = blk - 18; rowA = 4 + pair_c[m]; rowB = 4 + pair_cp[m]; out = 2304 + m * 128; prod = true; }
  for (int u = tid; u < 255; u += 128) {
    r0[u] = pos[rowA * 255 + u];
    r1[u] = pos[rowB * 255 + u];
  }
  __syncthreads();
  float s = 0.f;
  if (prod) {
    for (int d = 0; d < 128; ++d) s += r0[tid + d] * r1[tid + d];
  } else {
    for (int d = 0; d < 128; ++d) s += r0[tid + d];
  }
  PT[out + tid] = s;
}

// ---------------- K3: att stats, ONE (n,h) unit per wave, no atomics --------
__global__ __launch_bounds__(256) void k3_stats(
    const unsigned* __restrict__ y2h, const float* __restrict__ PT,
    float* __restrict__ Pb3)
{
  const int W = blockIdx.x * 4 + (threadIdx.x >> 6);
  const int lane = threadIdx.x & 63;
  const unsigned* yb = y2h + (size_t)W * 1024;
  float q[4][2], k[4][2];
#pragma unroll
  for (int pl = 0; pl < 2; ++pl) {
    half2_t ha = bch2(yb[pl * 128 + lane]);
    half2_t hb = bch2(yb[pl * 128 + 64 + lane]);
    q[2 * pl][0] = (float)ha[0]; q[2 * pl + 1][0] = (float)ha[1];
    q[2 * pl][1] = (float)hb[0]; q[2 * pl + 1][1] = (float)hb[1];
    half2_t hc = bch2(yb[(2 + pl) * 128 + lane]);
    half2_t hd = bch2(yb[(2 + pl) * 128 + 64 + lane]);
    k[2 * pl][0] = (float)hc[0]; k[2 * pl + 1][0] = (float)hc[1];
    k[2 * pl][1] = (float)hd[0]; k[2 * pl + 1][1] = (float)hd[1];
  }
  float vals[32];
#pragma unroll
  for (int c = 0; c < 4; ++c) {
    vals[c]     = q[c][0] + q[c][1];
    vals[4 + c] = k[c][0] + k[c][1];
  }
#pragma unroll
  for (int m = 0; m < 10; ++m) {
    int c = pair_c[m], cp = pair_cp[m];
    vals[8 + m]  = q[c][0] * q[cp][0] + q[c][1] * q[cp][1];
    vals[18 + m] = k[c][0] * k[cp][0] + k[c][1] * k[cp][1];
  }
  float qr = 0, qrss = 0, kr = 0, krss = 0;
#pragma unroll
  for (int c = 0; c < 4; ++c) {
    qr += q[c][0] * PT[c * 128 + lane]       + q[c][1] * PT[c * 128 + 64 + lane];
    kr += k[c][0] * PT[512 + c * 128 + lane] + k[c][1] * PT[512 + c * 128 + 64 + lane];
  }
#pragma unroll
  for (int m = 0; m < 10; ++m) {
    int c = pair_c[m], cp = pair_cp[m];
    float mult = (c == cp) ? 1.f : 2.f;
    qrss += mult * (q[c][0] * q[cp][0] * PT[1024 + m * 128 + lane]
                  + q[c][1] * q[cp][1] * PT[1024 + m * 128 + 64 + lane]);
    krss += mult * (k[c][0] * k[cp][0] * PT[2304 + m * 128 + lane]
                  + k[c][1] * k[cp][1] * PT[2304 + m * 128 + 64 + lane]);
  }
  vals[28] = qr; vals[29] = qrss; vals[30] = kr; vals[31] = krss;
#pragma unroll
  for (int v = 0; v < 32; ++v) {
    float t = vals[v];
#pragma unroll
    for (int off = 1; off < 64; off <<= 1) t += __shfl_xor(t, off);
    vals[v] = t;
  }
  if (lane == 0) {
    float qk_sum = 0, qk_ss = 0;
#pragma unroll
    for (int c = 0; c < 4; ++c) qk_sum += vals[c] * vals[4 + c];
#pragma unroll
    for (int m = 0; m < 10; ++m) {
      float mult = (pair_c[m] == pair_cp[m]) ? 1.f : 2.f;
      qk_ss += mult * vals[8 + m] * vals[18 + m];
    }
    float* o = Pb3 + W * 6;
    o[0] = qk_sum; o[1] = qk_ss;
    o[2] = vals[28]; o[3] = vals[29]; o[4] = vals[30]; o[5] = vals[31];
  }
}

// ---------------- KR1: reduce Pb3 (4096 units) + finalize att bn coefs ------
__global__ __launch_bounds__(384) void kR1(
    const float* __restrict__ Pb3, float* __restrict__ S,
    const float* __restrict__ ga, const float* __restrict__ ba,
    const float* __restrict__ gqr, const float* __restrict__ gkr)
{
  __shared__ float sums[48];
  const int t = threadIdx.x;
  const int col = t >> 3, sub = t & 7;
  if (col < 48) {
    const int h = col / 6, k = col % 6;
    float v = 0.f;
#pragma unroll
    for (int j = 0; j < 64; ++j) {
      int n = sub * 64 + j;
      v += Pb3[(size_t)(n * 8 + h) * 6 + k];
    }
    v += __shfl_xor(v, 1);
    v += __shfl_xor(v, 2);
    v += __shfl_xor(v, 4);
    if (sub == 0) sums[col] = v;
  }
  __syncthreads();
  if (t < 8) {
    const int h = t;
    const float inv = 1.f / 8388608.f;
    float gates[3] = {1.f, gqr[0], gkr[0]};
    float csum = 0.f;
#pragma unroll
    for (int g = 0; g < 3; ++g) {
      float mr = sums[h * 6 + 2 * g] * inv;
      float er = sums[h * 6 + 2 * g + 1] * inv;
      float gt = gates[g];
      float mean = gt * mr;
      float var = gt * gt * er - mean * mean;
      float sc = ga[g * 8 + h] * rsqrtf(var + EPS);
      S[560 + g * 8 + h] = gt * sc;
      csum += ba[g * 8 + h] - mean * sc;
    }
    S[584 + h] = csum;
  }
}

// ---------------- K5: TWO p-rows per thread (p even, p+1), dot2 PV ----------
// 256 threads: ph2 = tid>>2 (p=2*ph2), isub = tid&3; 16 i-pairs per thread.
// k-rows and vt-rows shared across the two p-rows; pos rows overlap (u+1,u,u-1).
__global__ __launch_bounds__(256, 5) void k5_apply(
    const unsigned* __restrict__ y2h, const unsigned* __restrict__ pos_h,
    const unsigned* __restrict__ vpxg,
    float* __restrict__ S, _Float16* __restrict__ av, _Float16* __restrict__ avp,
    const float* __restrict__ gv_p, const float* __restrict__ gvp_p,
    float* __restrict__ Vbuf)
{
  __shared__ __align__(16) unsigned qkv_s[128][12];
  __shared__ __align__(8)  unsigned posq[256][2];
  __shared__ __align__(8)  unsigned posk[256][2];
  __shared__ __align__(16) unsigned vt[64][12];
  __shared__ __align__(16) unsigned vpxf[3084];
  __shared__ float red[4][4];
  const int h = blockIdx.x & 7, n = blockIdx.x >> 3;
  const int tid = threadIdx.x;
  const unsigned* yb = y2h + (size_t)(n * 8 + h) * 1024;
  const float C0 = S[560 + h], C1 = S[568 + h], C2 = S[576 + h], C3v = S[584 + h];
  half2_t C0h, C1h, C2h;
  C0h[0] = C0h[1] = (_Float16)C0;
  C1h[0] = C1h[1] = (_Float16)C1;
  C2h[0] = C2h[1] = (_Float16)C2;
  for (int t = tid; t < 512; t += 256) {
    int l = t >> 2, s = t & 3;
    if (s == 0) {
      unsigned q01 = yb[l], q23 = yb[128 + l];
      qkv_s[l][0] = pkmul(q01, C0h); qkv_s[l][1] = pkmul(q23, C0h);
    } else if (s == 1) {
      unsigned q01 = yb[l], q23 = yb[128 + l];
      qkv_s[l][2] = pkmul(q01, C1h); qkv_s[l][3] = pkmul(q23, C1h);
    } else if (s == 2) {
      qkv_s[l][4] = yb[256 + l]; qkv_s[l][5] = yb[384 + l];
    } else {
      qkv_s[l][6] = pkmul(yb[256 + l], C2h); qkv_s[l][7] = pkmul(yb[384 + l], C2h);
    }
  }
  if (tid < 255) {
    uint4 t4 = *(const uint4*)&pos_h[tid * 4];
    posq[tid][0] = t4.x; posq[tid][1] = t4.y;
    posk[tid][0] = t4.z; posk[tid][1] = t4.w;
  }
  for (int m = tid; m < 3084; m += 256) vpxf[m] = vpxg[m];
  {
    int s = tid & 3, jp = tid >> 2;
    unsigned a0 = yb[(4 + s) * 128 + 2 * jp];
    unsigned a1 = yb[(4 + s) * 128 + 2 * jp + 1];
    vt[jp][2 * s]     = (a0 & 0xffffu) | (a1 << 16);
    vt[jp][2 * s + 1] = (a0 >> 16) | (a1 & 0xffff0000u);
  }
  __syncthreads();

  const int ph2 = tid >> 2, isub = tid & 3;
  const int p = 2 * ph2;
  uint4 qo0 = *(const uint4*)&qkv_s[p][0];
  uint2 kc0 = *(const uint2*)&qkv_s[p][6];
  uint4 qo1 = *(const uint4*)&qkv_s[p + 1][0];
  uint2 kc1 = *(const uint2*)&qkv_s[p + 1][6];
  const half2_t qa01_0 = bch2(qo0.x), qa23_0 = bch2(qo0.y);
  const half2_t qb01_0 = bch2(qo0.z), qb23_0 = bch2(qo0.w);
  const half2_t kc01_0 = bch2(kc0.x), kc23_0 = bch2(kc0.y);
  const half2_t qa01_1 = bch2(qo1.x), qa23_1 = bch2(qo1.y);
  const half2_t qb01_1 = bch2(qo1.z), qb23_1 = bch2(qo1.w);
  const half2_t kc01_1 = bch2(kc1.x), kc23_1 = bch2(kc1.y);
  const unsigned* vprow0 = &vpxf[(63 - ph2) * 12];
  const unsigned* vprow1 = &vpxf[1540 + (63 - ph2) * 12];
  const half2_t one2 = bch2(packf2(1.f, 1.f));

  float mcur0 = -1e30f, mcur1 = -1e30f;
  float sum0 = 0.f, sum1 = 0.f;
  float accv0[8], accvp0[8], accv1[8], accvp1[8];
#pragma unroll
  for (int c = 0; c < 8; ++c) {
    accv0[c] = 0.f; accvp0[c] = 0.f; accv1[c] = 0.f; accvp1[c] = 0.f;
  }

#pragma unroll
  for (int jj = 0; jj < 8; ++jj) {
    const int jpA = isub + 8 * jj;
    const int jpB = jpA + 4;
    const int i0A = 2 * jpA, i0B = 2 * jpB;
    const int uA = p - i0A + 127;
    const int uB = uA - 8;
    uint2 kaA = *(const uint2*)&qkv_s[i0A][4];
    uint2 kbA = *(const uint2*)&qkv_s[i0A + 1][4];
    uint2 kaB = *(const uint2*)&qkv_s[i0B][4];
    uint2 kbB = *(const uint2*)&qkv_s[i0B + 1][4];
    // pos rows: union {uA+1, uA, uA-1} and {uB+1, uB, uB-1}
    uint2 pqAp = *(const uint2*)&posq[uA + 1][0];
    uint2 pqA0 = *(const uint2*)&posq[uA][0];
    uint2 pqA1 = *(const uint2*)&posq[uA - 1][0];
    uint2 pqBp = *(const uint2*)&posq[uB + 1][0];
    uint2 pqB0 = *(const uint2*)&posq[uB][0];
    uint2 pqB1 = *(const uint2*)&posq[uB - 1][0];
    uint2 pkAp = *(const uint2*)&posk[uA + 1][0];
    uint2 pkA0 = *(const uint2*)&posk[uA][0];
    uint2 pkA1 = *(const uint2*)&posk[uA - 1][0];
    uint2 pkBp = *(const uint2*)&posk[uB + 1][0];
    uint2 pkB0 = *(const uint2*)&posk[uB][0];
    uint2 pkB1 = *(const uint2*)&posk[uB - 1][0];
    // row p scores
    float s0 = fdot2(qa01_0, bch2(kaA.x), fdot2(qa23_0, bch2(kaA.y),
               fdot2(qb01_0, bch2(pqA0.x), fdot2(qb23_0, bch2(pqA0.y),
               fdot2(kc01_0, bch2(pkA0.x), fdot2(kc23_0, bch2(pkA0.y), C3v))))));
    float s1 = fdot2(qa01_0, bch2(kbA.x), fdot2(qa23_0, bch2(kbA.y),
               fdot2(qb01_0, bch2(pqA1.x), fdot2(qb23_0, bch2(pqA1.y),
               fdot2(kc01_0, bch2(pkA1.x), fdot2(kc23_0, bch2(pkA1.y), C3v))))));
    float s2 = fdot2(qa01_0, bch2(kaB.x), fdot2(qa23_0, bch2(kaB.y),
               fdot2(qb01_0, bch2(pqB0.x), fdot2(qb23_0, bch2(pqB0.y),
               fdot2(kc01_0, bch2(pkB0.x), fdot2(kc23_0, bch2(pkB0.y), C3v))))));
    float s3 = fdot2(qa01_0, bch2(kbB.x), fdot2(qa23_0, bch2(kbB.y),
               fdot2(qb01_0, bch2(pqB1.x), fdot2(qb23_0, bch2(pqB1.y),
               fdot2(kc01_0, bch2(pkB1.x), fdot2(kc23_0, bch2(pkB1.y), C3v))))));
    // row p+1 scores (u shifted +1)
    float t0 = fdot2(qa01_1, bch2(kaA.x), fdot2(qa23_1, bch2(kaA.y),
               fdot2(qb01_1, bch2(pqAp.x), fdot2(qb23_1, bch2(pqAp.y),
               fdot2(kc01_1, bch2(pkAp.x), fdot2(kc23_1, bch2(pkAp.y), C3v))))));
    float t1 = fdot2(qa01_1, bch2(kbA.x), fdot2(qa23_1, bch2(kbA.y),
               fdot2(qb01_1, bch2(pqA0.x), fdot2(qb23_1, bch2(pqA0.y),
               fdot2(kc01_1, bch2(pkA0.x), fdot2(kc23_1, bch2(pkA0.y), C3v))))));
    float t2 = fdot2(qa01_1, bch2(kaB.x), fdot2(qa23_1, bch2(kaB.y),
               fdot2(qb01_1, bch2(pqBp.x), fdot2(qb23_1, bch2(pqBp.y),
               fdot2(kc01_1, bch2(pkBp.x), fdot2(kc23_1, bch2(pkBp.y), C3v))))));
    float t3 = fdot2(qa01_1, bch2(kbB.x), fdot2(qa23_1, bch2(kbB.y),
               fdot2(qb01_1, bch2(pqB0.x), fdot2(qb23_1, bch2(pqB0.y),
               fdot2(kc01_1, bch2(pkB0.x), fdot2(kc23_1, bch2(pkB0.y), C3v))))));
    // online max per row
    float mp0 = fmaxf(fmaxf(s0, s1), fmaxf(s2, s3));
    if (mp0 > mcur0) {
      float r = __expf(mcur0 - mp0);
      mcur0 = mp0;
      sum0 *= r;
#pragma unroll
      for (int c = 0; c < 8; ++c) { accv0[c] *= r; accvp0[c] *= r; }
    }
    float mp1 = fmaxf(fmaxf(t0, t1), fmaxf(t2, t3));
    if (mp1 > mcur1) {
      float r = __expf(mcur1 - mp1);
      mcur1 = mp1;
      sum1 *= r;
#pragma unroll
      for (int c = 0; c < 8; ++c) { accv1[c] *= r; accvp1[c] *= r; }
    }
    float e0 = __expf(s0 - mcur0), e1 = __expf(s1 - mcur0);
    float e2 = __expf(s2 - mcur0), e3 = __expf(s3 - mcur0);
    float f0 = __expf(t0 - mcur1), f1 = __expf(t1 - mcur1);
    float f2 = __expf(t2 - mcur1), f3 = __expf(t3 - mcur1);
    const half2_t eA0 = bch2(packf2(e0, e1)), eB0 = bch2(packf2(e2, e3));
    const half2_t eA1 = bch2(packf2(f0, f1)), eB1 = bch2(packf2(f2, f3));
    sum0 = fdot2(eB0, one2, fdot2(eA0, one2, sum0));
    sum1 = fdot2(eB1, one2, fdot2(eA1, one2, sum1));
    // shared v reads
    uint4 vaA = *(const uint4*)&vt[jpA][0];
    uint4 vbA = *(const uint4*)&vt[jpA][4];
    uint4 vaB = *(const uint4*)&vt[jpB][0];
    uint4 vbB = *(const uint4*)&vt[jpB][4];
    const unsigned* wrA0 = vprow0 + jpA * 12;
    const unsigned* wrB0 = vprow0 + jpB * 12;
    const unsigned* wrA1 = vprow1 + jpA * 12;
    const unsigned* wrB1 = vprow1 + jpB * 12;
    uint4 waA0 = *(const uint4*)wrA0, wbA0 = *(const uint4*)(wrA0 + 4);
    uint4 waB0 = *(const uint4*)wrB0, wbB0 = *(const uint4*)(wrB0 + 4);
    uint4 waA1 = *(const uint4*)wrA1, wbA1 = *(const uint4*)(wrA1 + 4);
    uint4 waB1 = *(const uint4*)wrB1, wbB1 = *(const uint4*)(wrB1 + 4);
    accv0[0] = fdot2(eB0, bch2(vaB.x), fdot2(eA0, bch2(vaA.x), accv0[0]));
    accv0[1] = fdot2(eB0, bch2(vaB.y), fdot2(eA0, bch2(vaA.y), accv0[1]));
    accv0[2] = fdot2(eB0, bch2(vaB.z), fdot2(eA0, bch2(vaA.z), accv0[2]));
    accv0[3] = fdot2(eB0, bch2(vaB.w), fdot2(eA0, bch2(vaA.w), accv0[3]));
    accv0[4] = fdot2(eB0, bch2(vbB.x), fdot2(eA0, bch2(vbA.x), accv0[4]));
    accv0[5] = fdot2(eB0, bch2(vbB.y), fdot2(eA0, bch2(vbA.y), accv0[5]));
    accv0[6] = fdot2(eB0, bch2(vbB.z), fdot2(eA0, bch2(vbA.z), accv0[6]));
    accv0[7] = fdot2(eB0, bch2(vbB.w), fdot2(eA0, bch2(vbA.w), accv0[7]));
    accv1[0] = fdot2(eB1, bch2(vaB.x), fdot2(eA1, bch2(vaA.x), accv1[0]));
    accv1[1] = fdot2(eB1, bch2(vaB.y), fdot2(eA1, bch2(vaA.y), accv1[1]));
    accv1[2] = fdot2(eB1, bch2(vaB.z), fdot2(eA1, bch2(vaA.z), accv1[2]));
    accv1[3] = fdot2(eB1, bch2(vaB.w), fdot2(eA1, bch2(vaA.w), accv1[3]));
    accv1[4] = fdot2(eB1, bch2(vbB.x), fdot2(eA1, bch2(vbA.x), accv1[4]));
    accv1[5] = fdot2(eB1, bch2(vbB.y), fdot2(eA1, bch2(vbA.y), accv1[5]));
    accv1[6] = fdot2(eB1, bch2(vbB.z), fdot2(eA1, bch2(vbA.z), accv1[6]));
    accv1[7] = fdot2(eB1, bch2(vbB.w), fdot2(eA1, bch2(vbA.w), accv1[7]));
    accvp0[0] = fdot2(eB0, bch2(waB0.x), fdot2(eA0, bch2(waA0.x), accvp0[0]));
    accvp0[1] = fdot2(eB0, bch2(waB0.y), fdot2(eA0, bch2(waA0.y), accvp0[1]));
    accvp0[2] = fdot2(eB0, bch2(waB0.z), fdot2(eA0, bch2(waA0.z), accvp0[2]));
    accvp0[3] = fdot2(eB0, bch2(waB0.w), fdot2(eA0, bch2(waA0.w), accvp0[3]));
    accvp0[4] = fdot2(eB0, bch2(wbB0.x), fdot2(eA0, bch2(wbA0.x), accvp0[4]));
    accvp0[5] = fdot2(eB0, bch2(wbB0.y), fdot2(eA0, bch2(wbA0.y), accvp0[5]));
    accvp0[6] = fdot2(eB0, bch2(wbB0.z), fdot2(eA0, bch2(wbA0.z), accvp0[6]));
    accvp0[7] = fdot2(eB0, bch2(wbB0.w), fdot2(eA0, bch2(wbA0.w), accvp0[7]));
    accvp1[0] = fdot2(eB1, bch2(waB1.x), fdot2(eA1, bch2(waA1.x), accvp1[0]));
    accvp1[1] = fdot2(eB1, bch2(waB1.y), fdot2(eA1, bch2(waA1.y), accvp1[1]));
    accvp1[2] = fdot2(eB1, bch2(waB1.z), fdot2(eA1, bch2(waA1.z), accvp1[2]));
    accvp1[3] = fdot2(eB1, bch2(waB1.w), fdot2(eA1, bch2(waA1.w), accvp1[3]));
    accvp1[4] = fdot2(eB1, bch2(wbB1.x), fdot2(eA1, bch2(wbA1.x), accvp1[4]));
    accvp1[5] = fdot2(eB1, bch2(wbB1.y), fdot2(eA1, bch2(wbA1.y), accvp1[5]));
    accvp1[6] = fdot2(eB1, bch2(wbB1.z), fdot2(eA1, bch2(wbA1.z), accvp1[6]));
    accvp1[7] = fdot2(eB1, bch2(wbB1.w), fdot2(eA1, bch2(wbA1.w), accvp1[7]));
  }
  // reconcile the 4 isub lanes per row
  float M0 = fmaxf(mcur0, __shfl_xor(mcur0, 1));
  M0 = fmaxf(M0, __shfl_xor(M0, 2));
  float M1 = fmaxf(mcur1, __shfl_xor(mcur1, 1));
  M1 = fmaxf(M1, __shfl_xor(M1, 2));
  {
    float r0 = __expf(mcur0 - M0), r1 = __expf(mcur1 - M1);
    sum0 *= r0; sum1 *= r1;
#pragma unroll
    for (int c = 0; c < 8; ++c) {
      accv0[c] *= r0; accvp0[c] *= r0;
      accv1[c] *= r1; accvp1[c] *= r1;
    }
  }
  sum0 += __shfl_xor(sum0, 1); sum0 += __shfl_xor(sum0, 2);
  sum1 += __shfl_xor(sum1, 1); sum1 += __shfl_xor(sum1, 2);
#pragma unroll
  for (int c = 0; c < 8; ++c) {
    accv0[c]  += __shfl_xor(accv0[c], 1);  accv0[c]  += __shfl_xor(accv0[c], 2);
    accvp0[c] += __shfl_xor(accvp0[c], 1); accvp0[c] += __shfl_xor(accvp0[c], 2);
    accv1[c]  += __shfl_xor(accv1[c], 1);  accv1[c]  += __shfl_xor(accv1[c], 2);
    accvp1[c] += __shfl_xor(accvp1[c], 1); accvp1[c] += __shfl_xor(accvp1[c], 2);
  }

  float sv = 0, ssv = 0, svp = 0, ssvp = 0;
  if (isub == 0) {
    const float gvv = gv_p[0], gvpv = gvp_p[0];
    const float fv0 = gvv / sum0, fp0 = gvpv / sum0;
    const float fv1 = gvv / sum1, fp1 = gvpv / sum1;
    size_t base = ((size_t)(n * 8 + h) * 8) * 128 + p;
#pragma unroll
    for (int c = 0; c < 8; ++c) {
      float a0 = accv0[c] * fv0,  a1 = accv1[c] * fv1;
      float b0 = accvp0[c] * fp0, b1 = accvp1[c] * fp1;
      *(unsigned*)&av [base + c * 128] = packf2(a0, a1);
      *(unsigned*)&avp[base + c * 128] = packf2(b0, b1);
      sv += a0 + a1; ssv += a0 * a0 + a1 * a1;
      svp += b0 + b1; ssvp += b0 * b0 + b1 * b1;
    }
  }
  float vals[4] = {sv, ssv, svp, ssvp};
#pragma unroll
  for (int kk = 0; kk < 4; ++kk) {
    float v = vals[kk];
#pragma unroll
    for (int off = 1; off < 64; off <<= 1) v += __shfl_xor(v, off);
    vals[kk] = v;
  }
  const int wid = tid >> 6, lane = tid & 63;
  if (lane == 0) {
#pragma unroll
    for (int kk = 0; kk < 4; ++kk) red[wid][kk] = vals[kk];
  }
  __syncthreads();
  if (tid == 0) {
    float t0 = 0, t1 = 0, t2 = 0, t3 = 0;
#pragma unroll
    for (int w = 0; w < 4; ++w) {
      t0 += red[w][0]; t1 += red[w][1]; t2 += red[w][2]; t3 += red[w][3];
    }
    float* o = Vbuf + (size_t)blockIdx.x * 4;
    o[0] = t0; o[1] = t1; o[2] = t2; o[3] = t3;
  }
}

// ---------------- KR2: reduce Vbuf + finalize v bn (merged) -----------------
__global__ __launch_bounds__(512) void kR2(
    const float* __restrict__ Vbuf, float* __restrict__ S,
    const float* __restrict__ gv, const float* __restrict__ bv)
{
  __shared__ float part[32][17];
  const int t = threadIdx.x;
  const int col = t >> 4, sub = t & 15;
  const int k = col >> 3, h = col & 7;
  float v = 0.f;
  for (int m = 0; m < 32; ++m) {
    int n = sub + 16 * m;
    v += Vbuf[(size_t)(n * 8 + h) * 4 + k];
  }
  part[col][sub] = v;
  __syncthreads();
  if (t < 32) {
    float s = 0.f;
#pragma unroll
    for (int j = 0; j < 16; ++j) s += part[t][j];
    part[t][16] = s;
  }
  __syncthreads();
  if (t < 8) {
    const int hh = t;
    const float inv = 1.f / 524288.f;
    float m1 = part[0 * 8 + hh][16] * inv;
    float e1 = part[1 * 8 + hh][16] * inv;
    float var = e1 - m1 * m1;
    float sc = gv[hh] * rsqrtf(var + EPS);
    S[624 + hh] = sc;
    S[632 + hh] = bv[hh] - m1 * sc;
    float m2 = part[2 * 8 + hh][16] * inv;
    float e2 = part[3 * 8 + hh][16] * inv;
    var = e2 - m2 * m2;
    sc = gv[8 + hh] * rsqrtf(var + EPS);
    S[640 + hh] = sc;
    S[648 + hh] = bv[8 + hh] - m2 * sc;
  }
}

// ---------------- K7: bn apply + sum halves + LDS-tiled transpose out -------
__global__ __launch_bounds__(256) void k7_out(
    const _Float16* __restrict__ av, const _Float16* __restrict__ avp,
    const float* __restrict__ S, float* __restrict__ out)
{
  __shared__ float tile[64][129];
  const int wt = blockIdx.x & 1;
  const int d  = (blockIdx.x >> 1) & 63;
  const int b  = blockIdx.x >> 7;
  const int h = d >> 3, c = d & 7;
  const float scv = S[624 + h], shv = S[632 + h];
  const float scp = S[640 + h], shp = S[648 + h];
  const int tid = threadIdx.x;
  for (int idx = tid; idx < 8192; idx += 256) {
    int wl = idx >> 7, pp = idx & 127;
    int n = b * 128 + wt * 64 + wl;
    size_t base = (((size_t)n * 8 + h) * 8 + c) * 128 + pp;
    tile[wl][pp] = (float)av[base] * scv + shv + (float)avp[base] * scp + shp;
  }
  __syncthreads();
  for (int idx = tid; idx < 8192; idx += 256) {
    int pp = idx >> 6, wl = idx & 63;
    out[(((size_t)b * 64 + d) * 128 + pp) * 128 + wt * 64 + wl] = tile[wl][pp];
  }
}

// ---------------- launch ----------------------------------------------------
extern "C" void kernel_launch(void* const* d_in, const int* in_sizes, int n_in,
                              void* d_out, int out_size, void* d_ws, size_t ws_size,
                              hipStream_t stream)
{
  const float* x   = (const float*)d_in[0];
  const float* wq  = (const float*)d_in[1];
  const float* g1  = (const float*)d_in[2];
  const float* b1  = (const float*)d_in[3];
  const float* pos = (const float*)d_in[4];
  const float* gqr = (const float*)d_in[5];
  const float* gkr = (const float*)d_in[6];
  const float* gvp = (const float*)d_in[7];
  const float* gv  = (const float*)d_in[8];
  const float* ga  = (const float*)d_in[9];
  const float* ba  = (const float*)d_in[10];
  const float* gv2 = (const float*)d_in[11];
  const float* bv2 = (const float*)d_in[12];

  float* ws = (float*)d_ws;
  _Float16* y1h   = (_Float16*)ws;
  _Float16* av    = (_Float16*)ws;
  _Float16* avp   = (_Float16*)ws + 4194304;
  float*    Pb3   = ws + 4200000;
  float*    Vbuf  = ws + 4250000;
  float*    Pbuf  = ws + 4300000;
  unsigned* y2h   = (unsigned*)(ws + 8388608);
  float*    S     = ws + 16777216;
  unsigned* pos_h = (unsigned*)(ws + 16778240);
  float*    PT    = ws + 16781312;
  unsigned* vpxg  = (unsigned*)(ws + 16785000);
  float*    out   = (float*)d_out;

  k0_pos<<<30, 128, 0, stream>>>(pos, PT, pos_h, vpxg);
  k1_gemm<<<512, 256, 0, stream>>>(x, wq, y1h, Pbuf);
  k_tr<<<256, 256, 0, stream>>>(y1h, Pbuf, g1, b1, y2h);
  k3_stats<<<1024, 256, 0, stream>>>(y2h, PT, Pb3);
  kR1<<<1, 384, 0, stream>>>(Pb3, S, ga, ba, gqr, gkr);
  k5_apply<<<4096, 256, 0, stream>>>(y2h, pos_h, vpxg, S, av, avp, gv, gvp, Vbuf);
  kR2<<<1, 512, 0, stream>>>(Vbuf, S, gv2, bv2);
  k7_out<<<512, 256, 0, stream>>>(av, avp, S, out);
}

// Round 16
// 190.841 us; speedup vs baseline: 3.0865x; 3.0865x over previous
//
#include <hip/hip_runtime.h>
#include <hip/hip_fp16.h>

#define EPS 1e-5f

// Problem constants: B=4, C=64, H=128, W=128, N=512, OP2=128, HEAD=8, HP=16
// qk_dim=4, v_dim=8

// workspace layout (float offsets)
//  y1h: (b,l,o,w) half, 8,388,608 halves at 0    [dead after k_tr]
//  av : (n,h,c,p) half, 4,194,304 halves at 0    (k5 writes; y1h region)
//  avp: (n,h,c,p) half at float-offset 2,097,152
//  Pb3: k3 partials 4096*6 f32 at 4,200,000
//  Vbuf: k5 partials 4096*4 f32 at 4,250,000
//  Pbuf: k1 partials 512*256 f32 at 4,300,000
//  y2h: (n,h,slot,l) packed half2 per uint, 1,048,576 uints at 8,388,608
//  S  : stats 1024 f32 at 16,777,216
//  pos_h: packed qk-pos [u][4 uints] at 16,778,240
//  PT : f32 window tables at 16,781,312
//  vpxg: flat vpx table (sel-shifted), 3084 uints at 16,785,000

typedef _Float16 half2_t __attribute__((ext_vector_type(2)));

__device__ __constant__ int pair_c [10] = {0,0,0,0,1,1,1,2,2,3};
__device__ __constant__ int pair_cp[10] = {0,1,2,3,1,2,3,2,3,3};

__device__ inline float fdot2(half2_t a, half2_t b, float c) {
#if __has_builtin(__builtin_amdgcn_fdot2)
  return __builtin_amdgcn_fdot2(a, b, c, false);
#else
  return c + (float)a[0] * (float)b[0] + (float)a[1] * (float)b[1];
#endif
}
__device__ inline half2_t bch2(unsigned u) {
  union { unsigned u; half2_t h; } x; x.u = u; return x.h;
}
__device__ inline unsigned bcu(half2_t h) {
  union { unsigned u; half2_t h; } x; x.h = h; return x.u;
}
__device__ inline unsigned packf2(float a, float b) {
  half2_t h; h[0] = (_Float16)a; h[1] = (_Float16)b;
  union { unsigned u; half2_t h; } x; x.h = h; return x.u;
}
__device__ inline unsigned pkmul(unsigned u, half2_t c) {
  return bcu(bch2(u) * c);
}

// ---------------- K1: qkv GEMM (half2 dot2) + relu + bn1 partials -----------
__global__ __launch_bounds__(256) void k1_gemm(
    const float* __restrict__ x, const float* __restrict__ wq,
    _Float16* __restrict__ y1h, float* __restrict__ Pbuf)
{
  __shared__ unsigned xs[32][132];
  const int b = blockIdx.x >> 7, l = blockIdx.x & 127;
  const int tid = threadIdx.x;
  const float* xp = x + (size_t)b * 1048576 + (size_t)l * 128;
  for (int idx = tid; idx < 1024; idx += 256) {
    int cp = idx >> 5, w4 = (idx & 31) * 4;
    float4 r0 = *(const float4*)&xp[(2 * cp) * 16384 + w4];
    float4 r1 = *(const float4*)&xp[(2 * cp + 1) * 16384 + w4];
    uint4 o;
    o.x = packf2(r0.x, r1.x); o.y = packf2(r0.y, r1.y);
    o.z = packf2(r0.z, r1.z); o.w = packf2(r0.w, r1.w);
    *(uint4*)&xs[cp][w4] = o;
  }
  __syncthreads();
  const int ty = tid >> 4, tx = tid & 15;
  const int o0 = ty * 8, w0 = tx * 4;
  float acc[8][8];
#pragma unroll
  for (int u = 0; u < 8; ++u)
#pragma unroll
    for (int v = 0; v < 8; ++v) acc[u][v] = 0.f;

  for (int c4 = 0; c4 < 64; c4 += 4) {
    unsigned wr[8][2];
#pragma unroll
    for (int u = 0; u < 8; ++u) {
      float4 wv = *(const float4*)&wq[(o0 + u) * 64 + c4];
      wr[u][0] = packf2(wv.x, wv.y);
      wr[u][1] = packf2(wv.z, wv.w);
    }
    const int cp0 = c4 >> 1;
#pragma unroll
    for (int d = 0; d < 2; ++d) {
      uint4 xa = *(const uint4*)&xs[cp0 + d][w0];
      uint4 xb = *(const uint4*)&xs[cp0 + d][w0 + 64];
      half2_t a0 = bch2(xa.x), a1 = bch2(xa.y), a2 = bch2(xa.z), a3 = bch2(xa.w);
      half2_t b0 = bch2(xb.x), b1 = bch2(xb.y), b2 = bch2(xb.z), b3 = bch2(xb.w);
#pragma unroll
      for (int u = 0; u < 8; ++u) {
        half2_t wh = bch2(wr[u][d]);
        acc[u][0] = fdot2(wh, a0, acc[u][0]);
        acc[u][1] = fdot2(wh, a1, acc[u][1]);
        acc[u][2] = fdot2(wh, a2, acc[u][2]);
        acc[u][3] = fdot2(wh, a3, acc[u][3]);
        acc[u][4] = fdot2(wh, b0, acc[u][4]);
        acc[u][5] = fdot2(wh, b1, acc[u][5]);
        acc[u][6] = fdot2(wh, b2, acc[u][6]);
        acc[u][7] = fdot2(wh, b3, acc[u][7]);
      }
    }
  }
  _Float16* y1p = y1h + (size_t)(b * 128 + l) * 16384;
#pragma unroll
  for (int u = 0; u < 8; ++u) {
#pragma unroll
    for (int v = 0; v < 8; ++v) acc[u][v] = fmaxf(acc[u][v], 0.f);
    uint2 pa, pb;
    pa.x = packf2(acc[u][0], acc[u][1]); pa.y = packf2(acc[u][2], acc[u][3]);
    pb.x = packf2(acc[u][4], acc[u][5]); pb.y = packf2(acc[u][6], acc[u][7]);
    *(uint2*)&y1p[(o0 + u) * 128 + w0] = pa;
    *(uint2*)&y1p[(o0 + u) * 128 + w0 + 64] = pb;
    float s  = acc[u][0] + acc[u][1] + acc[u][2] + acc[u][3]
             + acc[u][4] + acc[u][5] + acc[u][6] + acc[u][7];
    float ss = acc[u][0]*acc[u][0] + acc[u][1]*acc[u][1] + acc[u][2]*acc[u][2]
             + acc[u][3]*acc[u][3] + acc[u][4]*acc[u][4] + acc[u][5]*acc[u][5]
             + acc[u][6]*acc[u][6] + acc[u][7]*acc[u][7];
#pragma unroll
    for (int off = 1; off < 16; off <<= 1) {
      s  += __shfl_xor(s, off);
      ss += __shfl_xor(ss, off);
    }
    if (tx == 0) {
      Pbuf[blockIdx.x * 256 + o0 + u] = s;
      Pbuf[blockIdx.x * 256 + 128 + o0 + u] = ss;
    }
  }
}

// ---------------- K_tr: y1h -> y2h (BN stats reduced in-block, applied) -----
__global__ __launch_bounds__(256) void k_tr(
    const _Float16* __restrict__ y1h, const float* __restrict__ Pbuf,
    const float* __restrict__ g1, const float* __restrict__ b1,
    unsigned* __restrict__ y2h)
{
  __shared__ _Float16 th[2][64][134];
  __shared__ float scsh[4];
  const int s = blockIdx.x & 63, b = blockIdx.x >> 6;
  const int h = s >> 3, slot = s & 7;
  const int o0 = 2 * s, o1 = 2 * s + 1;
  const int tid = threadIdx.x;
  {
    int r = tid >> 6, lane = tid & 63;
    int row = ((r & 1) ? o1 : o0) + (r >> 1) * 128;
    float a = 0.f;
#pragma unroll
    for (int m = 0; m < 8; ++m) a += Pbuf[(lane + 64 * m) * 256 + row];
#pragma unroll
    for (int off = 1; off < 64; off <<= 1) a += __shfl_xor(a, off);
    if (lane == 0) scsh[r] = a;
  }
  __syncthreads();
  const float inv = 1.f / 65536.f;
  const float m0 = scsh[0] * inv, v0 = scsh[2] * inv - m0 * m0;
  const float m1 = scsh[1] * inv, v1 = scsh[3] * inv - m1 * m1;
  const float sc0 = g1[o0] * rsqrtf(v0 + EPS), sh0 = b1[o0] - m0 * sc0;
  const float sc1 = g1[o1] * rsqrtf(v1 + EPS), sh1 = b1[o1] - m1 * sc1;
  for (int lh = 0; lh < 2; ++lh) {
    const int l0 = lh * 64;
    for (int idx = tid; idx < 4096; idx += 256) {
      int ll = idx >> 6, wp = idx & 63;
      size_t base = ((size_t)(b * 128 + l0 + ll) * 128) * 128 + 2 * wp;
      unsigned a0 = *(const unsigned*)&y1h[base + (size_t)o0 * 128];
      unsigned a1 = *(const unsigned*)&y1h[base + (size_t)o1 * 128];
      half2_t ha = bch2(a0), hb = bch2(a1);
      *(unsigned*)&th[0][ll][2 * wp] =
          packf2((float)ha[0] * sc0 + sh0, (float)ha[1] * sc0 + sh0);
      *(unsigned*)&th[1][ll][2 * wp] =
          packf2((float)hb[0] * sc1 + sh1, (float)hb[1] * sc1 + sh1);
    }
    __syncthreads();
    for (int idx = tid; idx < 8192; idx += 256) {
      int w = idx >> 6, ll = idx & 63;
      unsigned pk;
      { half2_t hh; hh[0] = th[0][ll][w]; hh[1] = th[1][ll][w];
        union { unsigned u; half2_t h; } xx; xx.h = hh; pk = xx.u; }
      y2h[((size_t)((b * 128 + w) * 8 + h) * 8 + slot) * 128 + l0 + ll] = pk;
    }
    __syncthreads();
  }
}

// ---------------- K0: PT tables + packed qk-pos + vpx tables ----------------
__global__ __launch_bounds__(128) void k0_pos(const float* __restrict__ pos,
                                              float* __restrict__ PT,
                                              unsigned* __restrict__ pos_h,
                                              unsigned* __restrict__ vpxg)
{
  const int blk = blockIdx.x, tid = threadIdx.x;
  if (blk == 28) {
    for (int u = tid; u < 255; u += 128) {
#pragma unroll
      for (int s = 0; s < 4; ++s)
        pos_h[u * 4 + s] = packf2(pos[(2 * s) * 255 + u], pos[(2 * s + 1) * 255 + u]);
    }
    return;
  }
  if (blk == 29) {
    for (int m = tid; m < 3084; m += 128) {
      int sel = m / 1540, rem = m - sel * 1540;
      unsigned val = 0;
      if (sel < 2 && rem < 1536) {
        int rp = rem / 12, c = rem % 12;
        if (c < 8) {
          int ua = (sel ? 254 : 253) - 2 * rp;
          int ub = ua - 1;
          float fa = (ua >= 0) ? pos[(8 + c) * 255 + ua] : 0.f;
          float fb = (ub >= 0) ? pos[(8 + c) * 255 + ub] : 0.f;
          val = packf2(fa, fb);
        }
      }
      vpxg[m] = val;
    }
    return;
  }
  __shared__ float r0[255], r1[255];
  int rowA, rowB, out;
  bool prod;
  if (blk < 4)       { rowA = blk;                 rowB = rowA;               out = blk * 128;              prod = false; }
  else if (blk < 14) { int m = blk - 4;  rowA = pair_c[m];     rowB = pair_cp[m];     out = 1024 + m * 128; prod = true; }
  else if (blk < 18) { rowA = 4 + (blk - 14);      rowB = rowA;               out = 512 + (blk - 14) * 128; prod = false; }
  else               { int m = blk - 18; rowA = 4 + pair_c[m]; rowB = 4 + pair_cp[m]; out = 2304 + m * 128; prod = true; }
  for (int u = tid; u < 255; u += 128) {
    r0[u] = pos[rowA * 255 + u];
    r1[u] = pos[rowB * 255 + u];
  }
  __syncthreads();
  float s = 0.f;
  if (prod) {
    for (int d = 0; d < 128; ++d) s += r0[tid + d] * r1[tid + d];
  } else {
    for (int d = 0; d < 128; ++d) s += r0[tid + d];
  }
  PT[out + tid] = s;
}

// ---------------- K3: att stats, ONE (n,h) unit per wave, no atomics --------
__global__ __launch_bounds__(256) void k3_stats(
    const unsigned* __restrict__ y2h, const float* __restrict__ PT,
    float* __restrict__ Pb3)
{
  const int W = blockIdx.x * 4 + (threadIdx.x >> 6);
  const int lane = threadIdx.x & 63;
  const unsigned* yb = y2h + (size_t)W * 1024;
  float q[4][2], k[4][2];
#pragma unroll
  for (int pl = 0; pl < 2; ++pl) {
    half2_t ha = bch2(yb[pl * 128 + lane]);
    half2_t hb = bch2(yb[pl * 128 + 64 + lane]);
    q[2 * pl][0] = (float)ha[0]; q[2 * pl + 1][0] = (float)ha[1];
    q[2 * pl][1] = (float)hb[0]; q[2 * pl + 1][1] = (float)hb[1];
    half2_t hc = bch2(yb[(2 + pl) * 128 + lane]);
    half2_t hd = bch2(yb[(2 + pl) * 128 + 64 + lane]);
    k[2 * pl][0] = (float)hc[0]; k[2 * pl + 1][0] = (float)hc[1];
    k[2 * pl][1] = (float)hd[0]; k[2 * pl + 1][1] = (float)hd[1];
  }
  float vals[32];
#pragma unroll
  for (int c = 0; c < 4; ++c) {
    vals[c]     = q[c][0] + q[c][1];
    vals[4 + c] = k[c][0] + k[c][1];
  }
#pragma unroll
  for (int m = 0; m < 10; ++m) {
    int c = pair_c[m], cp = pair_cp[m];
    vals[8 + m]  = q[c][0] * q[cp][0] + q[c][1] * q[cp][1];
    vals[18 + m] = k[c][0] * k[cp][0] + k[c][1] * k[cp][1];
  }
  float qr = 0, qrss = 0, kr = 0, krss = 0;
#pragma unroll
  for (int c = 0; c < 4; ++c) {
    qr += q[c][0] * PT[c * 128 + lane]       + q[c][1] * PT[c * 128 + 64 + lane];
    kr += k[c][0] * PT[512 + c * 128 + lane] + k[c][1] * PT[512 + c * 128 + 64 + lane];
  }
#pragma unroll
  for (int m = 0; m < 10; ++m) {
    int c = pair_c[m], cp = pair_cp[m];
    float mult = (c == cp) ? 1.f : 2.f;
    qrss += mult * (q[c][0] * q[cp][0] * PT[1024 + m * 128 + lane]
                  + q[c][1] * q[cp][1] * PT[1024 + m * 128 + 64 + lane]);
    krss += mult * (k[c][0] * k[cp][0] * PT[2304 + m * 128 + lane]
                  + k[c][1] * k[cp][1] * PT[2304 + m * 128 + 64 + lane]);
  }
  vals[28] = qr; vals[29] = qrss; vals[30] = kr; vals[31] = krss;
#pragma unroll
  for (int v = 0; v < 32; ++v) {
    float t = vals[v];
#pragma unroll
    for (int off = 1; off < 64; off <<= 1) t += __shfl_xor(t, off);
    vals[v] = t;
  }
  if (lane == 0) {
    float qk_sum = 0, qk_ss = 0;
#pragma unroll
    for (int c = 0; c < 4; ++c) qk_sum += vals[c] * vals[4 + c];
#pragma unroll
    for (int m = 0; m < 10; ++m) {
      float mult = (pair_c[m] == pair_cp[m]) ? 1.f : 2.f;
      qk_ss += mult * vals[8 + m] * vals[18 + m];
    }
    float* o = Pb3 + W * 6;
    o[0] = qk_sum; o[1] = qk_ss;
    o[2] = vals[28]; o[3] = vals[29]; o[4] = vals[30]; o[5] = vals[31];
  }
}

// ---------------- KR1: reduce Pb3 (4096 units) + finalize att bn coefs ------
__global__ __launch_bounds__(384) void kR1(
    const float* __restrict__ Pb3, float* __restrict__ S,
    const float* __restrict__ ga, const float* __restrict__ ba,
    const float* __restrict__ gqr, const float* __restrict__ gkr)
{
  __shared__ float sums[48];
  const int t = threadIdx.x;
  const int col = t >> 3, sub = t & 7;
  if (col < 48) {
    const int h = col / 6, k = col % 6;
    float v = 0.f;
#pragma unroll
    for (int j = 0; j < 64; ++j) {
      int n = sub * 64 + j;
      v += Pb3[(size_t)(n * 8 + h) * 6 + k];
    }
    v += __shfl_xor(v, 1);
    v += __shfl_xor(v, 2);
    v += __shfl_xor(v, 4);
    if (sub == 0) sums[col] = v;
  }
  __syncthreads();
  if (t < 8) {
    const int h = t;
    const float inv = 1.f / 8388608.f;
    float gates[3] = {1.f, gqr[0], gkr[0]};
    float csum = 0.f;
#pragma unroll
    for (int g = 0; g < 3; ++g) {
      float mr = sums[h * 6 + 2 * g] * inv;
      float er = sums[h * 6 + 2 * g + 1] * inv;
      float gt = gates[g];
      float mean = gt * mr;
      float var = gt * gt * er - mean * mean;
      float sc = ga[g * 8 + h] * rsqrtf(var + EPS);
      S[560 + g * 8 + h] = gt * sc;
      csum += ba[g * 8 + h] - mean * sc;
    }
    S[584 + h] = csum;
  }
}

// ---------------- K5: TWO p-rows per thread (p even, p+1), dot2 PV ----------
// 256 threads: ph2 = tid>>2 (p=2*ph2), isub = tid&3; 16 i-pairs per thread.
// k-rows and vt-rows shared across the two p-rows; pos rows overlap.
// launch_bounds(256,3): 168-VGPR budget -> no spill (R15's (256,5) spilled).
__global__ __launch_bounds__(256, 3) void k5_apply(
    const unsigned* __restrict__ y2h, const unsigned* __restrict__ pos_h,
    const unsigned* __restrict__ vpxg,
    float* __restrict__ S, _Float16* __restrict__ av, _Float16* __restrict__ avp,
    const float* __restrict__ gv_p, const float* __restrict__ gvp_p,
    float* __restrict__ Vbuf)
{
  __shared__ __align__(16) unsigned qkv_s[128][12];
  __shared__ __align__(8)  unsigned posq[256][2];
  __shared__ __align__(8)  unsigned posk[256][2];
  __shared__ __align__(16) unsigned vt[64][12];
  __shared__ __align__(16) unsigned vpxf[3084];
  __shared__ float red[4][4];
  const int h = blockIdx.x & 7, n = blockIdx.x >> 3;
  const int tid = threadIdx.x;
  const unsigned* yb = y2h + (size_t)(n * 8 + h) * 1024;
  const float C0 = S[560 + h], C1 = S[568 + h], C2 = S[576 + h], C3v = S[584 + h];
  half2_t C0h, C1h, C2h;
  C0h[0] = C0h[1] = (_Float16)C0;
  C1h[0] = C1h[1] = (_Float16)C1;
  C2h[0] = C2h[1] = (_Float16)C2;
  for (int t = tid; t < 512; t += 256) {
    int l = t >> 2, s = t & 3;
    if (s == 0) {
      unsigned q01 = yb[l], q23 = yb[128 + l];
      qkv_s[l][0] = pkmul(q01, C0h); qkv_s[l][1] = pkmul(q23, C0h);
    } else if (s == 1) {
      unsigned q01 = yb[l], q23 = yb[128 + l];
      qkv_s[l][2] = pkmul(q01, C1h); qkv_s[l][3] = pkmul(q23, C1h);
    } else if (s == 2) {
      qkv_s[l][4] = yb[256 + l]; qkv_s[l][5] = yb[384 + l];
    } else {
      qkv_s[l][6] = pkmul(yb[256 + l], C2h); qkv_s[l][7] = pkmul(yb[384 + l], C2h);
    }
  }
  if (tid < 255) {
    uint4 t4 = *(const uint4*)&pos_h[tid * 4];
    posq[tid][0] = t4.x; posq[tid][1] = t4.y;
    posk[tid][0] = t4.z; posk[tid][1] = t4.w;
  }
  for (int m = tid; m < 3084; m += 256) vpxf[m] = vpxg[m];
  {
    int s = tid & 3, jp = tid >> 2;
    unsigned a0 = yb[(4 + s) * 128 + 2 * jp];
    unsigned a1 = yb[(4 + s) * 128 + 2 * jp + 1];
    vt[jp][2 * s]     = (a0 & 0xffffu) | (a1 << 16);
    vt[jp][2 * s + 1] = (a0 >> 16) | (a1 & 0xffff0000u);
  }
  __syncthreads();

  const int ph2 = tid >> 2, isub = tid & 3;
  const int p = 2 * ph2;
  uint4 qo0 = *(const uint4*)&qkv_s[p][0];
  uint2 kc0 = *(const uint2*)&qkv_s[p][6];
  uint4 qo1 = *(const uint4*)&qkv_s[p + 1][0];
  uint2 kc1 = *(const uint2*)&qkv_s[p + 1][6];
  const half2_t qa01_0 = bch2(qo0.x), qa23_0 = bch2(qo0.y);
  const half2_t qb01_0 = bch2(qo0.z), qb23_0 = bch2(qo0.w);
  const half2_t kc01_0 = bch2(kc0.x), kc23_0 = bch2(kc0.y);
  const half2_t qa01_1 = bch2(qo1.x), qa23_1 = bch2(qo1.y);
  const half2_t qb01_1 = bch2(qo1.z), qb23_1 = bch2(qo1.w);
  const half2_t kc01_1 = bch2(kc1.x), kc23_1 = bch2(kc1.y);
  const unsigned* vprow0 = &vpxf[(63 - ph2) * 12];
  const unsigned* vprow1 = &vpxf[1540 + (63 - ph2) * 12];
  const half2_t one2 = bch2(packf2(1.f, 1.f));

  float mcur0 = -1e30f, mcur1 = -1e30f;
  float sum0 = 0.f, sum1 = 0.f;
  float accv0[8], accvp0[8], accv1[8], accvp1[8];
#pragma unroll
  for (int c = 0; c < 8; ++c) {
    accv0[c] = 0.f; accvp0[c] = 0.f; accv1[c] = 0.f; accvp1[c] = 0.f;
  }

#pragma unroll
  for (int jj = 0; jj < 8; ++jj) {
    const int jpA = isub + 8 * jj;
    const int jpB = jpA + 4;
    const int i0A = 2 * jpA, i0B = 2 * jpB;
    const int uA = p - i0A + 127;
    const int uB = uA - 8;
    uint2 kaA = *(const uint2*)&qkv_s[i0A][4];
    uint2 kbA = *(const uint2*)&qkv_s[i0A + 1][4];
    uint2 kaB = *(const uint2*)&qkv_s[i0B][4];
    uint2 kbB = *(const uint2*)&qkv_s[i0B + 1][4];
    uint2 pqAp = *(const uint2*)&posq[uA + 1][0];
    uint2 pqA0 = *(const uint2*)&posq[uA][0];
    uint2 pqA1 = *(const uint2*)&posq[uA - 1][0];
    uint2 pqBp = *(const uint2*)&posq[uB + 1][0];
    uint2 pqB0 = *(const uint2*)&posq[uB][0];
    uint2 pqB1 = *(const uint2*)&posq[uB - 1][0];
    uint2 pkAp = *(const uint2*)&posk[uA + 1][0];
    uint2 pkA0 = *(const uint2*)&posk[uA][0];
    uint2 pkA1 = *(const uint2*)&posk[uA - 1][0];
    uint2 pkBp = *(const uint2*)&posk[uB + 1][0];
    uint2 pkB0 = *(const uint2*)&posk[uB][0];
    uint2 pkB1 = *(const uint2*)&posk[uB - 1][0];
    float s0 = fdot2(qa01_0, bch2(kaA.x), fdot2(qa23_0, bch2(kaA.y),
               fdot2(qb01_0, bch2(pqA0.x), fdot2(qb23_0, bch2(pqA0.y),
               fdot2(kc01_0, bch2(pkA0.x), fdot2(kc23_0, bch2(pkA0.y), C3v))))));
    float s1 = fdot2(qa01_0, bch2(kbA.x), fdot2(qa23_0, bch2(kbA.y),
               fdot2(qb01_0, bch2(pqA1.x), fdot2(qb23_0, bch2(pqA1.y),
               fdot2(kc01_0, bch2(pkA1.x), fdot2(kc23_0, bch2(pkA1.y), C3v))))));
    float s2 = fdot2(qa01_0, bch2(kaB.x), fdot2(qa23_0, bch2(kaB.y),
               fdot2(qb01_0, bch2(pqB0.x), fdot2(qb23_0, bch2(pqB0.y),
               fdot2(kc01_0, bch2(pkB0.x), fdot2(kc23_0, bch2(pkB0.y), C3v))))));
    float s3 = fdot2(qa01_0, bch2(kbB.x), fdot2(qa23_0, bch2(kbB.y),
               fdot2(qb01_0, bch2(pqB1.x), fdot2(qb23_0, bch2(pqB1.y),
               fdot2(kc01_0, bch2(pkB1.x), fdot2(kc23_0, bch2(pkB1.y), C3v))))));
    float t0 = fdot2(qa01_1, bch2(kaA.x), fdot2(qa23_1, bch2(kaA.y),
               fdot2(qb01_1, bch2(pqAp.x), fdot2(qb23_1, bch2(pqAp.y),
               fdot2(kc01_1, bch2(pkAp.x), fdot2(kc23_1, bch2(pkAp.y), C3v))))));
    float t1 = fdot2(qa01_1, bch2(kbA.x), fdot2(qa23_1, bch2(kbA.y),
               fdot2(qb01_1, bch2(pqA0.x), fdot2(qb23_1, bch2(pqA0.y),
               fdot2(kc01_1, bch2(pkA0.x), fdot2(kc23_1, bch2(pkA0.y), C3v))))));
    float t2 = fdot2(qa01_1, bch2(kaB.x), fdot2(qa23_1, bch2(kaB.y),
               fdot2(qb01_1, bch2(pqBp.x), fdot2(qb23_1, bch2(pqBp.y),
               fdot2(kc01_1, bch2(pkBp.x), fdot2(kc23_1, bch2(pkBp.y), C3v))))));
    float t3 = fdot2(qa01_1, bch2(kbB.x), fdot2(qa23_1, bch2(kbB.y),
               fdot2(qb01_1, bch2(pqB0.x), fdot2(qb23_1, bch2(pqB0.y),
               fdot2(kc01_1, bch2(pkB0.x), fdot2(kc23_1, bch2(pkB0.y), C3v))))));
    float mp0 = fmaxf(fmaxf(s0, s1), fmaxf(s2, s3));
    if (mp0 > mcur0) {
      float r = __expf(mcur0 - mp0);
      mcur0 = mp0;
      sum0 *= r;
#pragma unroll
      for (int c = 0; c < 8; ++c) { accv0[c] *= r; accvp0[c] *= r; }
    }
    float mp1 = fmaxf(fmaxf(t0, t1), fmaxf(t2, t3));
    if (mp1 > mcur1) {
      float r = __expf(mcur1 - mp1);
      mcur1 = mp1;
      sum1 *= r;
#pragma unroll
      for (int c = 0; c < 8; ++c) { accv1[c] *= r; accvp1[c] *= r; }
    }
    float e0 = __expf(s0 - mcur0), e1 = __expf(s1 - mcur0);
    float e2 = __expf(s2 - mcur0), e3 = __expf(s3 - mcur0);
    float f0 = __expf(t0 - mcur1), f1 = __expf(t1 - mcur1);
    float f2 = __expf(t2 - mcur1), f3 = __expf(t3 - mcur1);
    const half2_t eA0 = bch2(packf2(e0, e1)), eB0 = bch2(packf2(e2, e3));
    const half2_t eA1 = bch2(packf2(f0, f1)), eB1 = bch2(packf2(f2, f3));
    sum0 = fdot2(eB0, one2, fdot2(eA0, one2, sum0));
    sum1 = fdot2(eB1, one2, fdot2(eA1, one2, sum1));
    uint4 vaA = *(const uint4*)&vt[jpA][0];
    uint4 vbA = *(const uint4*)&vt[jpA][4];
    uint4 vaB = *(const uint4*)&vt[jpB][0];
    uint4 vbB = *(const uint4*)&vt[jpB][4];
    const unsigned* wrA0 = vprow0 + jpA * 12;
    const unsigned* wrB0 = vprow0 + jpB * 12;
    const unsigned* wrA1 = vprow1 + jpA * 12;
    const unsigned* wrB1 = vprow1 + jpB * 12;
    uint4 waA0 = *(const uint4*)wrA0, wbA0 = *(const uint4*)(wrA0 + 4);
    uint4 waB0 = *(const uint4*)wrB0, wbB0 = *(const uint4*)(wrB0 + 4);
    uint4 waA1 = *(const uint4*)wrA1, wbA1 = *(const uint4*)(wrA1 + 4);
    uint4 waB1 = *(const uint4*)wrB1, wbB1 = *(const uint4*)(wrB1 + 4);
    accv0[0] = fdot2(eB0, bch2(vaB.x), fdot2(eA0, bch2(vaA.x), accv0[0]));
    accv0[1] = fdot2(eB0, bch2(vaB.y), fdot2(eA0, bch2(vaA.y), accv0[1]));
    accv0[2] = fdot2(eB0, bch2(vaB.z), fdot2(eA0, bch2(vaA.z), accv0[2]));
    accv0[3] = fdot2(eB0, bch2(vaB.w), fdot2(eA0, bch2(vaA.w), accv0[3]));
    accv0[4] = fdot2(eB0, bch2(vbB.x), fdot2(eA0, bch2(vbA.x), accv0[4]));
    accv0[5] = fdot2(eB0, bch2(vbB.y), fdot2(eA0, bch2(vbA.y), accv0[5]));
    accv0[6] = fdot2(eB0, bch2(vbB.z), fdot2(eA0, bch2(vbA.z), accv0[6]));
    accv0[7] = fdot2(eB0, bch2(vbB.w), fdot2(eA0, bch2(vbA.w), accv0[7]));
    accv1[0] = fdot2(eB1, bch2(vaB.x), fdot2(eA1, bch2(vaA.x), accv1[0]));
    accv1[1] = fdot2(eB1, bch2(vaB.y), fdot2(eA1, bch2(vaA.y), accv1[1]));
    accv1[2] = fdot2(eB1, bch2(vaB.z), fdot2(eA1, bch2(vaA.z), accv1[2]));
    accv1[3] = fdot2(eB1, bch2(vaB.w), fdot2(eA1, bch2(vaA.w), accv1[3]));
    accv1[4] = fdot2(eB1, bch2(vbB.x), fdot2(eA1, bch2(vbA.x), accv1[4]));
    accv1[5] = fdot2(eB1, bch2(vbB.y), fdot2(eA1, bch2(vbA.y), accv1[5]));
    accv1[6] = fdot2(eB1, bch2(vbB.z), fdot2(eA1, bch2(vbA.z), accv1[6]));
    accv1[7] = fdot2(eB1, bch2(vbB.w), fdot2(eA1, bch2(vbA.w), accv1[7]));
    accvp0[0] = fdot2(eB0, bch2(waB0.x), fdot2(eA0, bch2(waA0.x), accvp0[0]));
    accvp0[1] = fdot2(eB0, bch2(waB0.y), fdot2(eA0, bch2(waA0.y), accvp0[1]));
    accvp0[2] = fdot2(eB0, bch2(waB0.z), fdot2(eA0, bch2(waA0.z), accvp0[2]));
    accvp0[3] = fdot2(eB0, bch2(waB0.w), fdot2(eA0, bch2(waA0.w), accvp0[3]));
    accvp0[4] = fdot2(eB0, bch2(wbB0.x), fdot2(eA0, bch2(wbA0.x), accvp0[4]));
    accvp0[5] = fdot2(eB0, bch2(wbB0.y), fdot2(eA0, bch2(wbA0.y), accvp0[5]));
    accvp0[6] = fdot2(eB0, bch2(wbB0.z), fdot2(eA0, bch2(wbA0.z), accvp0[6]));
    accvp0[7] = fdot2(eB0, bch2(wbB0.w), fdot2(eA0, bch2(wbA0.w), accvp0[7]));
    accvp1[0] = fdot2(eB1, bch2(waB1.x), fdot2(eA1, bch2(waA1.x), accvp1[0]));
    accvp1[1] = fdot2(eB1, bch2(waB1.y), fdot2(eA1, bch2(waA1.y), accvp1[1]));
    accvp1[2] = fdot2(eB1, bch2(waB1.z), fdot2(eA1, bch2(waA1.z), accvp1[2]));
    accvp1[3] = fdot2(eB1, bch2(waB1.w), fdot2(eA1, bch2(waA1.w), accvp1[3]));
    accvp1[4] = fdot2(eB1, bch2(wbB1.x), fdot2(eA1, bch2(wbA1.x), accvp1[4]));
    accvp1[5] = fdot2(eB1, bch2(wbB1.y), fdot2(eA1, bch2(wbA1.y), accvp1[5]));
    accvp1[6] = fdot2(eB1, bch2(wbB1.z), fdot2(eA1, bch2(wbA1.z), accvp1[6]));
    accvp1[7] = fdot2(eB1, bch2(wbB1.w), fdot2(eA1, bch2(wbA1.w), accvp1[7]));
  }
  float M0 = fmaxf(mcur0, __shfl_xor(mcur0, 1));
  M0 = fmaxf(M0, __shfl_xor(M0, 2));
  float M1 = fmaxf(mcur1, __shfl_xor(mcur1, 1));
  M1 = fmaxf(M1, __shfl_xor(M1, 2));
  {
    float r0 = __expf(mcur0 - M0), r1 = __expf(mcur1 - M1);
    sum0 *= r0; sum1 *= r1;
#pragma unroll
    for (int c = 0; c < 8; ++c) {
      accv0[c] *= r0; accvp0[c] *= r0;
      accv1[c] *= r1; accvp1[c] *= r1;
    }
  }
  sum0 += __shfl_xor(sum0, 1); sum0 += __shfl_xor(sum0, 2);
  sum1 += __shfl_xor(sum1, 1); sum1 += __shfl_xor(sum1, 2);
#pragma unroll
  for (int c = 0; c < 8; ++c) {
    accv0[c]  += __shfl_xor(accv0[c], 1);  accv0[c]  += __shfl_xor(accv0[c], 2);
    accvp0[c] += __shfl_xor(accvp0[c], 1); accvp0[c] += __shfl_xor(accvp0[c], 2);
    accv1[c]  += __shfl_xor(accv1[c], 1);  accv1[c]  += __shfl_xor(accv1[c], 2);
    accvp1[c] += __shfl_xor(accvp1[c], 1); accvp1[c] += __shfl_xor(accvp1[c], 2);
  }

  float sv = 0, ssv = 0, svp = 0, ssvp = 0;
  if (isub == 0) {
    const float gvv = gv_p[0], gvpv = gvp_p[0];
    const float fv0 = gvv / sum0, fp0 = gvpv / sum0;
    const float fv1 = gvv / sum1, fp1 = gvpv / sum1;
    size_t base = ((size_t)(n * 8 + h) * 8) * 128 + p;
#pragma unroll
    for (int c = 0; c < 8; ++c) {
      float a0 = accv0[c] * fv0,  a1 = accv1[c] * fv1;
      float b0 = accvp0[c] * fp0, b1 = accvp1[c] * fp1;
      *(unsigned*)&av [base + c * 128] = packf2(a0, a1);
      *(unsigned*)&avp[base + c * 128] = packf2(b0, b1);
      sv += a0 + a1; ssv += a0 * a0 + a1 * a1;
      svp += b0 + b1; ssvp += b0 * b0 + b1 * b1;
    }
  }
  float vals[4] = {sv, ssv, svp, ssvp};
#pragma unroll
  for (int kk = 0; kk < 4; ++kk) {
    float v = vals[kk];
#pragma unroll
    for (int off = 1; off < 64; off <<= 1) v += __shfl_xor(v, off);
    vals[kk] = v;
  }
  const int wid = tid >> 6, lane = tid & 63;
  if (lane == 0) {
#pragma unroll
    for (int kk = 0; kk < 4; ++kk) red[wid][kk] = vals[kk];
  }
  __syncthreads();
  if (tid == 0) {
    float t0 = 0, t1 = 0, t2 = 0, t3 = 0;
#pragma unroll
    for (int w = 0; w < 4; ++w) {
      t0 += red[w][0]; t1 += red[w][1]; t2 += red[w][2]; t3 += red[w][3];
    }
    float* o = Vbuf + (size_t)blockIdx.x * 4;
    o[0] = t0; o[1] = t1; o[2] = t2; o[3] = t3;
  }
}

// ---------------- KR2: reduce Vbuf + finalize v bn (merged) -----------------
__global__ __launch_bounds__(512) void kR2(
    const float* __restrict__ Vbuf, float* __restrict__ S,
    const float* __restrict__ gv, const float* __restrict__ bv)
{
  __shared__ float part[32][17];
  const int t = threadIdx.x;
  const int col = t >> 4, sub = t & 15;
  const int k = col >> 3, h = col & 7;
  float v = 0.f;
  for (int m = 0; m < 32; ++m) {
    int n = sub + 16 * m;
    v += Vbuf[(size_t)(n * 8 + h) * 4 + k];
  }
  part[col][sub] = v;
  __syncthreads();
  if (t < 32) {
    float s = 0.f;
#pragma unroll
    for (int j = 0; j < 16; ++j) s += part[t][j];
    part[t][16] = s;
  }
  __syncthreads();
  if (t < 8) {
    const int hh = t;
    const float inv = 1.f / 524288.f;
    float m1 = part[0 * 8 + hh][16] * inv;
    float e1 = part[1 * 8 + hh][16] * inv;
    float var = e1 - m1 * m1;
    float sc = gv[hh] * rsqrtf(var + EPS);
    S[624 + hh] = sc;
    S[632 + hh] = bv[hh] - m1 * sc;
    float m2 = part[2 * 8 + hh][16] * inv;
    float e2 = part[3 * 8 + hh][16] * inv;
    var = e2 - m2 * m2;
    sc = gv[8 + hh] * rsqrtf(var + EPS);
    S[640 + hh] = sc;
    S[648 + hh] = bv[8 + hh] - m2 * sc;
  }
}

// ---------------- K7: bn apply + sum halves + LDS-tiled transpose out -------
__global__ __launch_bounds__(256) void k7_out(
    const _Float16* __restrict__ av, const _Float16* __restrict__ avp,
    const float* __restrict__ S, float* __restrict__ out)
{
  __shared__ float tile[64][129];
  const int wt = blockIdx.x & 1;
  const int d  = (blockIdx.x >> 1) & 63;
  const int b  = blockIdx.x >> 7;
  const int h = d >> 3, c = d & 7;
  const float scv = S[624 + h], shv = S[632 + h];
  const float scp = S[640 + h], shp = S[648 + h];
  const int tid = threadIdx.x;
  for (int idx = tid; idx < 8192; idx += 256) {
    int wl = idx >> 7, pp = idx & 127;
    int n = b * 128 + wt * 64 + wl;
    size_t base = (((size_t)n * 8 + h) * 8 + c) * 128 + pp;
    tile[wl][pp] = (float)av[base] * scv + shv + (float)avp[base] * scp + shp;
  }
  __syncthreads();
  for (int idx = tid; idx < 8192; idx += 256) {
    int pp = idx >> 6, wl = idx & 63;
    out[(((size_t)b * 64 + d) * 128 + pp) * 128 + wt * 64 + wl] = tile[wl][pp];
  }
}

// ---------------- launch ----------------------------------------------------
extern "C" void kernel_launch(void* const* d_in, const int* in_sizes, int n_in,
                              void* d_out, int out_size, void* d_ws, size_t ws_size,
                              hipStream_t stream)
{
  const float* x   = (const float*)d_in[0];
  const float* wq  = (const float*)d_in[1];
  const float* g1  = (const float*)d_in[2];
  const float* b1  = (const float*)d_in[3];
  const float* pos = (const float*)d_in[4];
  const float* gqr = (const float*)d_in[5];
  const float* gkr = (const float*)d_in[6];
  const float* gvp = (const float*)d_in[7];
  const float* gv  = (const float*)d_in[8];
  const float* ga  = (const float*)d_in[9];
  const float* ba  = (const float*)d_in[10];
  const float* gv2 = (const float*)d_in[11];
  const float* bv2 = (const float*)d_in[12];

  float* ws = (float*)d_ws;
  _Float16* y1h   = (_Float16*)ws;
  _Float16* av    = (_Float16*)ws;
  _Float16* avp   = (_Float16*)ws + 4194304;
  float*    Pb3   = ws + 4200000;
  float*    Vbuf  = ws + 4250000;
  float*    Pbuf  = ws + 4300000;
  unsigned* y2h   = (unsigned*)(ws + 8388608);
  float*    S     = ws + 16777216;
  unsigned* pos_h = (unsigned*)(ws + 16778240);
  float*    PT    = ws + 16781312;
  unsigned* vpxg  = (unsigned*)(ws + 16785000);
  float*    out   = (float*)d_out;

  k0_pos<<<30, 128, 0, stream>>>(pos, PT, pos_h, vpxg);
  k1_gemm<<<512, 256, 0, stream>>>(x, wq, y1h, Pbuf);
  k_tr<<<256, 256, 0, stream>>>(y1h, Pbuf, g1, b1, y2h);
  k3_stats<<<1024, 256, 0, stream>>>(y2h, PT, Pb3);
  kR1<<<1, 384, 0, stream>>>(Pb3, S, ga, ba, gqr, gkr);
  k5_apply<<<4096, 256, 0, stream>>>(y2h, pos_h, vpxg, S, av, avp, gv, gvp, Vbuf);
  kR2<<<1, 512, 0, stream>>>(Vbuf, S, gv2, bv2);
  k7_out<<<512, 256, 0, stream>>>(av, avp, S, out);
}

// Round 17
// 175.484 us; speedup vs baseline: 3.3566x; 1.0875x over previous
//
#include <hip/hip_runtime.h>
#include <hip/hip_fp16.h>

#define EPS 1e-5f

// Problem constants: B=4, C=64, H=128, W=128, N=512, OP2=128, HEAD=8, HP=16
// qk_dim=4, v_dim=8

// workspace layout (float offsets)
//  y1h: (b,l,o,w) half, 8,388,608 halves at 0    [dead after k_tr]
//  av : (n,h,c,p) half, 4,194,304 halves at 0    (k5 writes; y1h region)
//  avp: (n,h,c,p) half at float-offset 2,097,152
//  Pb3: k3 partials 4096*6 f32 at 4,200,000
//  Vbuf: k5 partials 4096*4 f32 at 4,250,000
//  Pbuf: k1 partials 512*256 f32 at 4,300,000
//  y2h: (n,h,slot,l) packed half2 per uint, 1,048,576 uints at 8,388,608
//  S  : stats 1024 f32 at 16,777,216
//  pos_h: packed qk-pos [u][4 uints] at 16,778,240
//  PT : f32 window tables at 16,781,312
//  vpxg: flat vpx table (sel-shifted), 3084 uints at 16,785,000

typedef _Float16 half2_t __attribute__((ext_vector_type(2)));

__device__ __constant__ int pair_c [10] = {0,0,0,0,1,1,1,2,2,3};
__device__ __constant__ int pair_cp[10] = {0,1,2,3,1,2,3,2,3,3};

__device__ inline float fdot2(half2_t a, half2_t b, float c) {
#if __has_builtin(__builtin_amdgcn_fdot2)
  return __builtin_amdgcn_fdot2(a, b, c, false);
#else
  return c + (float)a[0] * (float)b[0] + (float)a[1] * (float)b[1];
#endif
}
__device__ inline half2_t bch2(unsigned u) {
  union { unsigned u; half2_t h; } x; x.u = u; return x.h;
}
__device__ inline unsigned bcu(half2_t h) {
  union { unsigned u; half2_t h; } x; x.h = h; return x.u;
}
__device__ inline unsigned packf2(float a, float b) {
  half2_t h; h[0] = (_Float16)a; h[1] = (_Float16)b;
  union { unsigned u; half2_t h; } x; x.h = h; return x.u;
}
__device__ inline unsigned pkmul(unsigned u, half2_t c) {
  return bcu(bch2(u) * c);   // v_pk_mul_f16
}

// ---------------- K1: qkv GEMM (half2 dot2) + relu + bn1 partials -----------
__global__ __launch_bounds__(256) void k1_gemm(
    const float* __restrict__ x, const float* __restrict__ wq,
    _Float16* __restrict__ y1h, float* __restrict__ Pbuf)
{
  __shared__ unsigned xs[32][132];
  const int b = blockIdx.x >> 7, l = blockIdx.x & 127;
  const int tid = threadIdx.x;
  const float* xp = x + (size_t)b * 1048576 + (size_t)l * 128;
  for (int idx = tid; idx < 1024; idx += 256) {
    int cp = idx >> 5, w4 = (idx & 31) * 4;
    float4 r0 = *(const float4*)&xp[(2 * cp) * 16384 + w4];
    float4 r1 = *(const float4*)&xp[(2 * cp + 1) * 16384 + w4];
    uint4 o;
    o.x = packf2(r0.x, r1.x); o.y = packf2(r0.y, r1.y);
    o.z = packf2(r0.z, r1.z); o.w = packf2(r0.w, r1.w);
    *(uint4*)&xs[cp][w4] = o;
  }
  __syncthreads();
  const int ty = tid >> 4, tx = tid & 15;
  const int o0 = ty * 8, w0 = tx * 4;
  float acc[8][8];
#pragma unroll
  for (int u = 0; u < 8; ++u)
#pragma unroll
    for (int v = 0; v < 8; ++v) acc[u][v] = 0.f;

  for (int c4 = 0; c4 < 64; c4 += 4) {
    unsigned wr[8][2];
#pragma unroll
    for (int u = 0; u < 8; ++u) {
      float4 wv = *(const float4*)&wq[(o0 + u) * 64 + c4];
      wr[u][0] = packf2(wv.x, wv.y);
      wr[u][1] = packf2(wv.z, wv.w);
    }
    const int cp0 = c4 >> 1;
#pragma unroll
    for (int d = 0; d < 2; ++d) {
      uint4 xa = *(const uint4*)&xs[cp0 + d][w0];
      uint4 xb = *(const uint4*)&xs[cp0 + d][w0 + 64];
      half2_t a0 = bch2(xa.x), a1 = bch2(xa.y), a2 = bch2(xa.z), a3 = bch2(xa.w);
      half2_t b0 = bch2(xb.x), b1 = bch2(xb.y), b2 = bch2(xb.z), b3 = bch2(xb.w);
#pragma unroll
      for (int u = 0; u < 8; ++u) {
        half2_t wh = bch2(wr[u][d]);
        acc[u][0] = fdot2(wh, a0, acc[u][0]);
        acc[u][1] = fdot2(wh, a1, acc[u][1]);
        acc[u][2] = fdot2(wh, a2, acc[u][2]);
        acc[u][3] = fdot2(wh, a3, acc[u][3]);
        acc[u][4] = fdot2(wh, b0, acc[u][4]);
        acc[u][5] = fdot2(wh, b1, acc[u][5]);
        acc[u][6] = fdot2(wh, b2, acc[u][6]);
        acc[u][7] = fdot2(wh, b3, acc[u][7]);
      }
    }
  }
  _Float16* y1p = y1h + (size_t)(b * 128 + l) * 16384;
#pragma unroll
  for (int u = 0; u < 8; ++u) {
#pragma unroll
    for (int v = 0; v < 8; ++v) acc[u][v] = fmaxf(acc[u][v], 0.f);
    uint2 pa, pb;
    pa.x = packf2(acc[u][0], acc[u][1]); pa.y = packf2(acc[u][2], acc[u][3]);
    pb.x = packf2(acc[u][4], acc[u][5]); pb.y = packf2(acc[u][6], acc[u][7]);
    *(uint2*)&y1p[(o0 + u) * 128 + w0] = pa;
    *(uint2*)&y1p[(o0 + u) * 128 + w0 + 64] = pb;
    float s  = acc[u][0] + acc[u][1] + acc[u][2] + acc[u][3]
             + acc[u][4] + acc[u][5] + acc[u][6] + acc[u][7];
    float ss = acc[u][0]*acc[u][0] + acc[u][1]*acc[u][1] + acc[u][2]*acc[u][2]
             + acc[u][3]*acc[u][3] + acc[u][4]*acc[u][4] + acc[u][5]*acc[u][5]
             + acc[u][6]*acc[u][6] + acc[u][7]*acc[u][7];
#pragma unroll
    for (int off = 1; off < 16; off <<= 1) {
      s  += __shfl_xor(s, off);
      ss += __shfl_xor(ss, off);
    }
    if (tx == 0) {
      Pbuf[blockIdx.x * 256 + o0 + u] = s;
      Pbuf[blockIdx.x * 256 + 128 + o0 + u] = ss;
    }
  }
}

// ---------------- K_tr: y1h -> y2h (BN stats reduced in-block, applied) -----
__global__ __launch_bounds__(256) void k_tr(
    const _Float16* __restrict__ y1h, const float* __restrict__ Pbuf,
    const float* __restrict__ g1, const float* __restrict__ b1,
    unsigned* __restrict__ y2h)
{
  __shared__ _Float16 th[2][64][134];
  __shared__ float scsh[4];
  const int s = blockIdx.x & 63, b = blockIdx.x >> 6;
  const int h = s >> 3, slot = s & 7;
  const int o0 = 2 * s, o1 = 2 * s + 1;
  const int tid = threadIdx.x;
  {
    int r = tid >> 6, lane = tid & 63;
    int row = ((r & 1) ? o1 : o0) + (r >> 1) * 128;
    float a = 0.f;
#pragma unroll
    for (int m = 0; m < 8; ++m) a += Pbuf[(lane + 64 * m) * 256 + row];
#pragma unroll
    for (int off = 1; off < 64; off <<= 1) a += __shfl_xor(a, off);
    if (lane == 0) scsh[r] = a;
  }
  __syncthreads();
  const float inv = 1.f / 65536.f;
  const float m0 = scsh[0] * inv, v0 = scsh[2] * inv - m0 * m0;
  const float m1 = scsh[1] * inv, v1 = scsh[3] * inv - m1 * m1;
  const float sc0 = g1[o0] * rsqrtf(v0 + EPS), sh0 = b1[o0] - m0 * sc0;
  const float sc1 = g1[o1] * rsqrtf(v1 + EPS), sh1 = b1[o1] - m1 * sc1;
  for (int lh = 0; lh < 2; ++lh) {
    const int l0 = lh * 64;
    for (int idx = tid; idx < 4096; idx += 256) {
      int ll = idx >> 6, wp = idx & 63;
      size_t base = ((size_t)(b * 128 + l0 + ll) * 128) * 128 + 2 * wp;
      unsigned a0 = *(const unsigned*)&y1h[base + (size_t)o0 * 128];
      unsigned a1 = *(const unsigned*)&y1h[base + (size_t)o1 * 128];
      half2_t ha = bch2(a0), hb = bch2(a1);
      *(unsigned*)&th[0][ll][2 * wp] =
          packf2((float)ha[0] * sc0 + sh0, (float)ha[1] * sc0 + sh0);
      *(unsigned*)&th[1][ll][2 * wp] =
          packf2((float)hb[0] * sc1 + sh1, (float)hb[1] * sc1 + sh1);
    }
    __syncthreads();
    for (int idx = tid; idx < 8192; idx += 256) {
      int w = idx >> 6, ll = idx & 63;
      unsigned pk;
      { half2_t hh; hh[0] = th[0][ll][w]; hh[1] = th[1][ll][w];
        union { unsigned u; half2_t h; } xx; xx.h = hh; pk = xx.u; }
      y2h[((size_t)((b * 128 + w) * 8 + h) * 8 + slot) * 128 + l0 + ll] = pk;
    }
    __syncthreads();
  }
}

// ---------------- K0: PT tables + packed qk-pos + vpx tables ----------------
__global__ __launch_bounds__(128) void k0_pos(const float* __restrict__ pos,
                                              float* __restrict__ PT,
                                              unsigned* __restrict__ pos_h,
                                              unsigned* __restrict__ vpxg)
{
  const int blk = blockIdx.x, tid = threadIdx.x;
  if (blk == 28) {
    for (int u = tid; u < 255; u += 128) {
#pragma unroll
      for (int s = 0; s < 4; ++s)
        pos_h[u * 4 + s] = packf2(pos[(2 * s) * 255 + u], pos[(2 * s + 1) * 255 + u]);
    }
    return;
  }
  if (blk == 29) {
    // flat vpx, sel-shifted: index = sel*1540 + rp*12 + c
    for (int m = tid; m < 3084; m += 128) {
      int sel = m / 1540, rem = m - sel * 1540;
      unsigned val = 0;
      if (sel < 2 && rem < 1536) {
        int rp = rem / 12, c = rem % 12;
        if (c < 8) {
          int ua = (sel ? 254 : 253) - 2 * rp;
          int ub = ua - 1;
          float fa = (ua >= 0) ? pos[(8 + c) * 255 + ua] : 0.f;
          float fb = (ub >= 0) ? pos[(8 + c) * 255 + ub] : 0.f;
          val = packf2(fa, fb);
        }
      }
      vpxg[m] = val;
    }
    return;
  }
  __shared__ float r0[255], r1[255];
  int rowA, rowB, out;
  bool prod;
  if (blk < 4)       { rowA = blk;                 rowB = rowA;               out = blk * 128;              prod = false; }
  else if (blk < 14) { int m = blk - 4;  rowA = pair_c[m];     rowB = pair_cp[m];     out = 1024 + m * 128; prod = true; }
  else if (blk < 18) { rowA = 4 + (blk - 14);      rowB = rowA;               out = 512 + (blk - 14) * 128; prod = false; }
  else               { int m = blk - 18; rowA = 4 + pair_c[m]; rowB = 4 + pair_cp[m]; out = 2304 + m * 128; prod = true; }
  for (int u = tid; u < 255; u += 128) {
    r0[u] = pos[rowA * 255 + u];
    r1[u] = pos[rowB * 255 + u];
  }
  __syncthreads();
  float s = 0.f;
  if (prod) {
    for (int d = 0; d < 128; ++d) s += r0[tid + d] * r1[tid + d];
  } else {
    for (int d = 0; d < 128; ++d) s += r0[tid + d];
  }
  PT[out + tid] = s;
}

// ---------------- K3: att stats, ONE (n,h) unit per wave, no atomics --------
__global__ __launch_bounds__(256) void k3_stats(
    const unsigned* __restrict__ y2h, const float* __restrict__ PT,
    float* __restrict__ Pb3)
{
  const int W = blockIdx.x * 4 + (threadIdx.x >> 6);
  const int lane = threadIdx.x & 63;
  const unsigned* yb = y2h + (size_t)W * 1024;
  float q[4][2], k[4][2];
#pragma unroll
  for (int pl = 0; pl < 2; ++pl) {
    half2_t ha = bch2(yb[pl * 128 + lane]);
    half2_t hb = bch2(yb[pl * 128 + 64 + lane]);
    q[2 * pl][0] = (float)ha[0]; q[2 * pl + 1][0] = (float)ha[1];
    q[2 * pl][1] = (float)hb[0]; q[2 * pl + 1][1] = (float)hb[1];
    half2_t hc = bch2(yb[(2 + pl) * 128 + lane]);
    half2_t hd = bch2(yb[(2 + pl) * 128 + 64 + lane]);
    k[2 * pl][0] = (float)hc[0]; k[2 * pl + 1][0] = (float)hc[1];
    k[2 * pl][1] = (float)hd[0]; k[2 * pl + 1][1] = (float)hd[1];
  }
  float vals[32];
#pragma unroll
  for (int c = 0; c < 4; ++c) {
    vals[c]     = q[c][0] + q[c][1];
    vals[4 + c] = k[c][0] + k[c][1];
  }
#pragma unroll
  for (int m = 0; m < 10; ++m) {
    int c = pair_c[m], cp = pair_cp[m];
    vals[8 + m]  = q[c][0] * q[cp][0] + q[c][1] * q[cp][1];
    vals[18 + m] = k[c][0] * k[cp][0] + k[c][1] * k[cp][1];
  }
  float qr = 0, qrss = 0, kr = 0, krss = 0;
#pragma unroll
  for (int c = 0; c < 4; ++c) {
    qr += q[c][0] * PT[c * 128 + lane]       + q[c][1] * PT[c * 128 + 64 + lane];
    kr += k[c][0] * PT[512 + c * 128 + lane] + k[c][1] * PT[512 + c * 128 + 64 + lane];
  }
#pragma unroll
  for (int m = 0; m < 10; ++m) {
    int c = pair_c[m], cp = pair_cp[m];
    float mult = (c == cp) ? 1.f : 2.f;
    qrss += mult * (q[c][0] * q[cp][0] * PT[1024 + m * 128 + lane]
                  + q[c][1] * q[cp][1] * PT[1024 + m * 128 + 64 + lane]);
    krss += mult * (k[c][0] * k[cp][0] * PT[2304 + m * 128 + lane]
                  + k[c][1] * k[cp][1] * PT[2304 + m * 128 + 64 + lane]);
  }
  vals[28] = qr; vals[29] = qrss; vals[30] = kr; vals[31] = krss;
#pragma unroll
  for (int v = 0; v < 32; ++v) {
    float t = vals[v];
#pragma unroll
    for (int off = 1; off < 64; off <<= 1) t += __shfl_xor(t, off);
    vals[v] = t;
  }
  if (lane == 0) {
    float qk_sum = 0, qk_ss = 0;
#pragma unroll
    for (int c = 0; c < 4; ++c) qk_sum += vals[c] * vals[4 + c];
#pragma unroll
    for (int m = 0; m < 10; ++m) {
      float mult = (pair_c[m] == pair_cp[m]) ? 1.f : 2.f;
      qk_ss += mult * vals[8 + m] * vals[18 + m];
    }
    float* o = Pb3 + W * 6;
    o[0] = qk_sum; o[1] = qk_ss;
    o[2] = vals[28]; o[3] = vals[29]; o[4] = vals[30]; o[5] = vals[31];
  }
}

// ---------------- KR1: reduce Pb3 (4096 units) + finalize att bn coefs ------
__global__ __launch_bounds__(384) void kR1(
    const float* __restrict__ Pb3, float* __restrict__ S,
    const float* __restrict__ ga, const float* __restrict__ ba,
    const float* __restrict__ gqr, const float* __restrict__ gkr)
{
  __shared__ float sums[48];
  const int t = threadIdx.x;
  const int col = t >> 3, sub = t & 7;
  if (col < 48) {
    const int h = col / 6, k = col % 6;
    float v = 0.f;
#pragma unroll
    for (int j = 0; j < 64; ++j) {
      int n = sub * 64 + j;
      v += Pb3[(size_t)(n * 8 + h) * 6 + k];
    }
    v += __shfl_xor(v, 1);
    v += __shfl_xor(v, 2);
    v += __shfl_xor(v, 4);
    if (sub == 0) sums[col] = v;
  }
  __syncthreads();
  if (t < 8) {
    const int h = t;
    const float inv = 1.f / 8388608.f;
    float gates[3] = {1.f, gqr[0], gkr[0]};
    float csum = 0.f;
#pragma unroll
    for (int g = 0; g < 3; ++g) {
      float mr = sums[h * 6 + 2 * g] * inv;
      float er = sums[h * 6 + 2 * g + 1] * inv;
      float gt = gates[g];
      float mean = gt * mr;
      float var = gt * gt * er - mean * mean;
      float sc = ga[g * 8 + h] * rsqrtf(var + EPS);
      S[560 + g * 8 + h] = gt * sc;
      csum += ba[g * 8 + h] - mean * sc;
    }
    S[584 + h] = csum;
  }
}

// ---------------- K5: C-folded operands, online-max softmax, dot2 PV --------
// qkv_s rows (32B): 0 qa01 1 qa23 (q*C0) 2 qb01 3 qb23 (q*C1)
//                   4 k01 5 k23 (raw)    6 kc01 7 kc23 (k*C2)
__global__ __launch_bounds__(512, 6) void k5_apply(
    const unsigned* __restrict__ y2h, const unsigned* __restrict__ pos_h,
    const unsigned* __restrict__ vpxg,
    float* __restrict__ S, _Float16* __restrict__ av, _Float16* __restrict__ avp,
    const float* __restrict__ gv_p, const float* __restrict__ gvp_p,
    float* __restrict__ Vbuf)
{
  __shared__ __align__(16) unsigned qkv_s[128][8];
  __shared__ __align__(16) unsigned posm[255][4];
  __shared__ __align__(16) unsigned vt[64][8];
  __shared__ __align__(16) unsigned vpxf[3084];  // flat, sel-shifted (1540/sel)
  __shared__ float red[8][4];
  const int h = blockIdx.x & 7, n = blockIdx.x >> 3;
  const int tid = threadIdx.x;
  const unsigned* yb = y2h + (size_t)(n * 8 + h) * 1024;
  const float C0 = S[560 + h], C1 = S[568 + h], C2 = S[576 + h], C3v = S[584 + h];
  half2_t C0h, C1h, C2h;
  C0h[0] = C0h[1] = (_Float16)C0;
  C1h[0] = C1h[1] = (_Float16)C1;
  C2h[0] = C2h[1] = (_Float16)C2;
  {
    int l = tid >> 2, s = tid & 3;
    if (s == 0) {
      unsigned q01 = yb[l], q23 = yb[128 + l];
      qkv_s[l][0] = pkmul(q01, C0h); qkv_s[l][1] = pkmul(q23, C0h);
    } else if (s == 1) {
      unsigned q01 = yb[l], q23 = yb[128 + l];
      qkv_s[l][2] = pkmul(q01, C1h); qkv_s[l][3] = pkmul(q23, C1h);
    } else if (s == 2) {
      qkv_s[l][4] = yb[256 + l]; qkv_s[l][5] = yb[384 + l];
    } else {
      qkv_s[l][6] = pkmul(yb[256 + l], C2h); qkv_s[l][7] = pkmul(yb[384 + l], C2h);
    }
  }
  {
    unsigned* pf = (unsigned*)posm;
    for (int m = tid; m < 1020; m += 512) pf[m] = pos_h[m];
  }
  for (int m = tid; m < 3084; m += 512) vpxf[m] = vpxg[m];
  if (tid < 256) {
    int s = tid & 3, jp = tid >> 2;
    unsigned a0 = yb[(4 + s) * 128 + 2 * jp];
    unsigned a1 = yb[(4 + s) * 128 + 2 * jp + 1];
    vt[jp][2 * s]     = (a0 & 0xffffu) | (a1 << 16);
    vt[jp][2 * s + 1] = (a0 >> 16) | (a1 & 0xffff0000u);
  }
  __syncthreads();

  const int p = tid >> 2, isub = tid & 3;
  uint4 qown = *(const uint4*)&qkv_s[p][0];
  uint2 kco  = *(const uint2*)&qkv_s[p][6];
  const half2_t qa01 = bch2(qown.x), qa23 = bch2(qown.y);
  const half2_t qb01 = bch2(qown.z), qb23 = bch2(qown.w);
  const half2_t kc01 = bch2(kco.x),  kc23 = bch2(kco.y);
  const unsigned* vprow = &vpxf[(p & 1) * 1540 + (63 - (p >> 1)) * 12];
  const half2_t one2 = bch2(packf2(1.f, 1.f));

  float mcur = -1e30f;
  float sum = 0.f;
  float accv[8], accvp[8];
#pragma unroll
  for (int c = 0; c < 8; ++c) { accv[c] = 0.f; accvp[c] = 0.f; }

#pragma unroll
  for (int jj = 0; jj < 8; ++jj) {
    const int jpA = isub + 8 * jj;
    const int jpB = jpA + 4;
    const int i0A = 2 * jpA, i0B = 2 * jpB;
    const int uA = p - i0A + 127;
    const int uB = uA - 8;
    uint2 kaA = *(const uint2*)&qkv_s[i0A][4];
    uint2 kbA = *(const uint2*)&qkv_s[i0A + 1][4];
    uint2 kaB = *(const uint2*)&qkv_s[i0B][4];
    uint2 kbB = *(const uint2*)&qkv_s[i0B + 1][4];
    uint4 paA = *(const uint4*)&posm[uA][0];
    uint4 pbA = *(const uint4*)&posm[uA - 1][0];
    uint4 paB = *(const uint4*)&posm[uB][0];
    uint4 pbB = *(const uint4*)&posm[uB - 1][0];
    float s0 = fdot2(qa01, bch2(kaA.x), fdot2(qa23, bch2(kaA.y),
               fdot2(qb01, bch2(paA.x), fdot2(qb23, bch2(paA.y),
               fdot2(kc01, bch2(paA.z), fdot2(kc23, bch2(paA.w), C3v))))));
    float s1 = fdot2(qa01, bch2(kbA.x), fdot2(qa23, bch2(kbA.y),
               fdot2(qb01, bch2(pbA.x), fdot2(qb23, bch2(pbA.y),
               fdot2(kc01, bch2(pbA.z), fdot2(kc23, bch2(pbA.w), C3v))))));
    float s2 = fdot2(qa01, bch2(kaB.x), fdot2(qa23, bch2(kaB.y),
               fdot2(qb01, bch2(paB.x), fdot2(qb23, bch2(paB.y),
               fdot2(kc01, bch2(paB.z), fdot2(kc23, bch2(paB.w), C3v))))));
    float s3 = fdot2(qa01, bch2(kbB.x), fdot2(qa23, bch2(kbB.y),
               fdot2(qb01, bch2(pbB.x), fdot2(qb23, bch2(pbB.y),
               fdot2(kc01, bch2(pbB.z), fdot2(kc23, bch2(pbB.w), C3v))))));
    float mp = fmaxf(fmaxf(s0, s1), fmaxf(s2, s3));
    if (mp > mcur) {
      float r = __expf(mcur - mp);
      mcur = mp;
      sum *= r;
#pragma unroll
      for (int c = 0; c < 8; ++c) { accv[c] *= r; accvp[c] *= r; }
    }
    float e0 = __expf(s0 - mcur);
    float e1 = __expf(s1 - mcur);
    float e2f = __expf(s2 - mcur);
    float e3f = __expf(s3 - mcur);
    const half2_t eA = bch2(packf2(e0, e1));
    const half2_t eB = bch2(packf2(e2f, e3f));
    sum = fdot2(eB, one2, fdot2(eA, one2, sum));
    uint4 vaA = *(const uint4*)&vt[jpA][0];
    uint4 vbA = *(const uint4*)&vt[jpA][4];
    uint4 vaB = *(const uint4*)&vt[jpB][0];
    uint4 vbB = *(const uint4*)&vt[jpB][4];
    const unsigned* wrA = vprow + jpA * 12;
    const unsigned* wrB = vprow + jpB * 12;
    uint4 waA = *(const uint4*)wrA;
    uint4 wbA = *(const uint4*)(wrA + 4);
    uint4 waB = *(const uint4*)wrB;
    uint4 wbB = *(const uint4*)(wrB + 4);
    accv[0] = fdot2(eB, bch2(vaB.x), fdot2(eA, bch2(vaA.x), accv[0]));
    accv[1] = fdot2(eB, bch2(vaB.y), fdot2(eA, bch2(vaA.y), accv[1]));
    accv[2] = fdot2(eB, bch2(vaB.z), fdot2(eA, bch2(vaA.z), accv[2]));
    accv[3] = fdot2(eB, bch2(vaB.w), fdot2(eA, bch2(vaA.w), accv[3]));
    accv[4] = fdot2(eB, bch2(vbB.x), fdot2(eA, bch2(vbA.x), accv[4]));
    accv[5] = fdot2(eB, bch2(vbB.y), fdot2(eA, bch2(vbA.y), accv[5]));
    accv[6] = fdot2(eB, bch2(vbB.z), fdot2(eA, bch2(vbA.z), accv[6]));
    accv[7] = fdot2(eB, bch2(vbB.w), fdot2(eA, bch2(vbA.w), accv[7]));
    accvp[0] = fdot2(eB, bch2(waB.x), fdot2(eA, bch2(waA.x), accvp[0]));
    accvp[1] = fdot2(eB, bch2(waB.y), fdot2(eA, bch2(waA.y), accvp[1]));
    accvp[2] = fdot2(eB, bch2(waB.z), fdot2(eA, bch2(waA.z), accvp[2]));
    accvp[3] = fdot2(eB, bch2(waB.w), fdot2(eA, bch2(waA.w), accvp[3]));
    accvp[4] = fdot2(eB, bch2(wbB.x), fdot2(eA, bch2(wbA.x), accvp[4]));
    accvp[5] = fdot2(eB, bch2(wbB.y), fdot2(eA, bch2(wbA.y), accvp[5]));
    accvp[6] = fdot2(eB, bch2(wbB.z), fdot2(eA, bch2(wbA.z), accvp[6]));
    accvp[7] = fdot2(eB, bch2(wbB.w), fdot2(eA, bch2(wbA.w), accvp[7]));
  }
  float M = fmaxf(mcur, __shfl_xor(mcur, 1));
  M = fmaxf(M, __shfl_xor(M, 2));
  {
    float r = __expf(mcur - M);
    sum *= r;
#pragma unroll
    for (int c = 0; c < 8; ++c) { accv[c] *= r; accvp[c] *= r; }
  }
  sum += __shfl_xor(sum, 1);
  sum += __shfl_xor(sum, 2);
#pragma unroll
  for (int c = 0; c < 8; ++c) {
    accv[c]  += __shfl_xor(accv[c], 1);  accv[c]  += __shfl_xor(accv[c], 2);
    accvp[c] += __shfl_xor(accvp[c], 1); accvp[c] += __shfl_xor(accvp[c], 2);
  }

  float sv = 0, ssv = 0, svp = 0, ssvp = 0;
  if (isub == 0) {
    const float fv = gv_p[0] / sum, fp2 = gvp_p[0] / sum;
    size_t base = ((size_t)(n * 8 + h) * 8) * 128 + p;
#pragma unroll
    for (int c = 0; c < 8; ++c) {
      float x1 = accv[c] * fv;
      float x2 = accvp[c] * fp2;
      av [base + c * 128] = (_Float16)x1;
      avp[base + c * 128] = (_Float16)x2;
      sv += x1; ssv += x1 * x1; svp += x2; ssvp += x2 * x2;
    }
  }
  float vals[4] = {sv, ssv, svp, ssvp};
#pragma unroll
  for (int kk = 0; kk < 4; ++kk) {
    float v = vals[kk];
#pragma unroll
    for (int off = 1; off < 64; off <<= 1) v += __shfl_xor(v, off);
    vals[kk] = v;
  }
  const int wid = tid >> 6, lane = tid & 63;
  if (lane == 0) {
#pragma unroll
    for (int kk = 0; kk < 4; ++kk) red[wid][kk] = vals[kk];
  }
  __syncthreads();
  if (tid == 0) {
    float t0 = 0, t1 = 0, t2 = 0, t3 = 0;
#pragma unroll
    for (int w = 0; w < 8; ++w) {
      t0 += red[w][0]; t1 += red[w][1]; t2 += red[w][2]; t3 += red[w][3];
    }
    float* o = Vbuf + (size_t)blockIdx.x * 4;
    o[0] = t0; o[1] = t1; o[2] = t2; o[3] = t3;
  }
}

// ---------------- KR2: reduce Vbuf + finalize v bn (merged) -----------------
__global__ __launch_bounds__(512) void kR2(
    const float* __restrict__ Vbuf, float* __restrict__ S,
    const float* __restrict__ gv, const float* __restrict__ bv)
{
  __shared__ float part[32][17];
  const int t = threadIdx.x;
  const int col = t >> 4, sub = t & 15;
  const int k = col >> 3, h = col & 7;
  float v = 0.f;
  for (int m = 0; m < 32; ++m) {
    int n = sub + 16 * m;
    v += Vbuf[(size_t)(n * 8 + h) * 4 + k];
  }
  part[col][sub] = v;
  __syncthreads();
  if (t < 32) {
    float s = 0.f;
#pragma unroll
    for (int j = 0; j < 16; ++j) s += part[t][j];
    part[t][16] = s;
  }
  __syncthreads();
  if (t < 8) {
    const int hh = t;
    const float inv = 1.f / 524288.f;
    float m1 = part[0 * 8 + hh][16] * inv;
    float e1 = part[1 * 8 + hh][16] * inv;
    float var = e1 - m1 * m1;
    float sc = gv[hh] * rsqrtf(var + EPS);
    S[624 + hh] = sc;
    S[632 + hh] = bv[hh] - m1 * sc;
    float m2 = part[2 * 8 + hh][16] * inv;
    float e2 = part[3 * 8 + hh][16] * inv;
    var = e2 - m2 * m2;
    sc = gv[8 + hh] * rsqrtf(var + EPS);
    S[640 + hh] = sc;
    S[648 + hh] = bv[8 + hh] - m2 * sc;
  }
}

// ---------------- K7: bn apply + sum halves + LDS-tiled transpose out -------
__global__ __launch_bounds__(256) void k7_out(
    const _Float16* __restrict__ av, const _Float16* __restrict__ avp,
    const float* __restrict__ S, float* __restrict__ out)
{
  __shared__ float tile[64][129];
  const int wt = blockIdx.x & 1;
  const int d  = (blockIdx.x >> 1) & 63;
  const int b  = blockIdx.x >> 7;
  const int h = d >> 3, c = d & 7;
  const float scv = S[624 + h], shv = S[632 + h];
  const float scp = S[640 + h], shp = S[648 + h];
  const int tid = threadIdx.x;
  for (int idx = tid; idx < 8192; idx += 256) {
    int wl = idx >> 7, pp = idx & 127;
    int n = b * 128 + wt * 64 + wl;
    size_t base = (((size_t)n * 8 + h) * 8 + c) * 128 + pp;
    tile[wl][pp] = (float)av[base] * scv + shv + (float)avp[base] * scp + shp;
  }
  __syncthreads();
  for (int idx = tid; idx < 8192; idx += 256) {
    int pp = idx >> 6, wl = idx & 63;
    out[(((size_t)b * 64 + d) * 128 + pp) * 128 + wt * 64 + wl] = tile[wl][pp];
  }
}

// ---------------- launch ----------------------------------------------------
extern "C" void kernel_launch(void* const* d_in, const int* in_sizes, int n_in,
                              void* d_out, int out_size, void* d_ws, size_t ws_size,
                              hipStream_t stream)
{
  const float* x   = (const float*)d_in[0];
  const float* wq  = (const float*)d_in[1];
  const float* g1  = (const float*)d_in[2];
  const float* b1  = (const float*)d_in[3];
  const float* pos = (const float*)d_in[4];
  const float* gqr = (const float*)d_in[5];
  const float* gkr = (const float*)d_in[6];
  const float* gvp = (const float*)d_in[7];
  const float* gv  = (const float*)d_in[8];
  const float* ga  = (const float*)d_in[9];
  const float* ba  = (const float*)d_in[10];
  const float* gv2 = (const float*)d_in[11];
  const float* bv2 = (const float*)d_in[12];

  float* ws = (float*)d_ws;
  _Float16* y1h   = (_Float16*)ws;
  _Float16* av    = (_Float16*)ws;
  _Float16* avp   = (_Float16*)ws + 4194304;
  float*    Pb3   = ws + 4200000;
  float*    Vbuf  = ws + 4250000;
  float*    Pbuf  = ws + 4300000;
  unsigned* y2h   = (unsigned*)(ws + 8388608);
  float*    S     = ws + 16777216;
  unsigned* pos_h = (unsigned*)(ws + 16778240);
  float*    PT    = ws + 16781312;
  unsigned* vpxg  = (unsigned*)(ws + 16785000);
  float*    out   = (float*)d_out;

  k0_pos<<<30, 128, 0, stream>>>(pos, PT, pos_h, vpxg);
  k1_gemm<<<512, 256, 0, stream>>>(x, wq, y1h, Pbuf);
  k_tr<<<256, 256, 0, stream>>>(y1h, Pbuf, g1, b1, y2h);
  k3_stats<<<1024, 256, 0, stream>>>(y2h, PT, Pb3);
  kR1<<<1, 384, 0, stream>>>(Pb3, S, ga, ba, gqr, gkr);
  k5_apply<<<4096, 512, 0, stream>>>(y2h, pos_h, vpxg, S, av, avp, gv, gvp, Vbuf);
  kR2<<<1, 512, 0, stream>>>(Vbuf, S, gv2, bv2);
  k7_out<<<512, 256, 0, stream>>>(av, avp, S, out);
}